// Round 3
// baseline (1405.792 us; speedup 1.0000x reference)
//
#include <hip/hip_runtime.h>

constexpr int NN = 50000;   // nodes
constexpr int EE = 400000;  // edges
constexpr int DD = 128;     // feature dim
constexpr int HH = 4;       // heads
constexpr int LL = 3;       // layers
constexpr int QV = DD * HH; // 512
constexpr float NEG_SLOPE = 0.01f;
constexpr float LN_EPS = 1e-5f;

static inline int cdiv(int a, int b) { return (a + b - 1) / b; }

#define DEVINL __device__ __forceinline__

DEVINL float wave_sum(float v) {
#pragma unroll
  for (int off = 32; off; off >>= 1) v += __shfl_xor(v, off, 64);
  return v;
}
DEVINL float wave_max(float v) {
#pragma unroll
  for (int off = 32; off; off >>= 1) v = fmaxf(v, __shfl_xor(v, off, 64));
  return v;
}

DEVINL float bf2f(unsigned short u) {
  unsigned int t = ((unsigned int)u) << 16;
  float f;
  __builtin_memcpy(&f, &t, 4);
  return f;
}
DEVINL unsigned short f2bf(float f) {
  unsigned int u;
  __builtin_memcpy(&u, &f, 4);
  u = u + 0x7fffu + ((u >> 16) & 1u);  // RNE
  return (unsigned short)(u >> 16);
}

// ---------------------------------------------------------------------------
// Tiled GEMM: C[M,N] = A[M,K] @ B[K,N] (+bias / relu / +resid per EPI)
// TA in {float, ushort(bf16)}; TC in {float, ushort(bf16)}. B, bias, resid f32.
// EPI: 0 = +bias (if non-null), 1 = relu(+bias), 2 = +resid
// BM=BN=64, BK=16, 4x4 per thread, 256 threads.
// ---------------------------------------------------------------------------
template <typename TA, typename TC, int EPI>
__global__ __launch_bounds__(256) void gemm_t(
    const TA* __restrict__ A, const float* __restrict__ B,
    const float* __restrict__ bias, const float* __restrict__ resid,
    TC* __restrict__ C, int M, int N, int K) {
  constexpr int BM = 64, BN = 64, BK = 16, TM = 4, TN = 4;
  __shared__ float As[BK][BM];
  __shared__ float Bs[BK][BN];
  const int tid = threadIdx.x;
  const int brow = blockIdx.y * BM, bcol = blockIdx.x * BN;
  const int tr = (tid / 16) * TM;
  const int tc = (tid % 16) * TN;
  const int aRow = tid / 4;
  const int aCol = (tid % 4) * 4;
  const int bRow = tid / 16;
  const int bCol = (tid % 16) * 4;

  float acc[TM][TN] = {};
  for (int k0 = 0; k0 < K; k0 += BK) {
    int ar = brow + aRow;
    float av[4] = {0.f, 0.f, 0.f, 0.f};
    if (ar < M) {
      if constexpr (sizeof(TA) == 4) {
        float4 t = *reinterpret_cast<const float4*>(A + (size_t)ar * K + k0 + aCol);
        av[0] = t.x; av[1] = t.y; av[2] = t.z; av[3] = t.w;
      } else {
        ushort4 t = *reinterpret_cast<const ushort4*>(A + (size_t)ar * K + k0 + aCol);
        av[0] = bf2f(t.x); av[1] = bf2f(t.y); av[2] = bf2f(t.z); av[3] = bf2f(t.w);
      }
    }
    As[aCol + 0][aRow] = av[0];
    As[aCol + 1][aRow] = av[1];
    As[aCol + 2][aRow] = av[2];
    As[aCol + 3][aRow] = av[3];
    float4 bv = *reinterpret_cast<const float4*>(B + (size_t)(k0 + bRow) * N + bcol + bCol);
    *reinterpret_cast<float4*>(&Bs[bRow][bCol]) = bv;
    __syncthreads();
#pragma unroll
    for (int k = 0; k < BK; k++) {
      float4 ra = *reinterpret_cast<const float4*>(&As[k][tr]);
      float4 rb = *reinterpret_cast<const float4*>(&Bs[k][tc]);
      float rav[4] = {ra.x, ra.y, ra.z, ra.w};
      float rbv[4] = {rb.x, rb.y, rb.z, rb.w};
#pragma unroll
      for (int i = 0; i < TM; i++)
#pragma unroll
        for (int j = 0; j < TN; j++) acc[i][j] += rav[i] * rbv[j];
    }
    __syncthreads();
  }
#pragma unroll
  for (int i = 0; i < TM; i++) {
    int r = brow + tr + i;
    if (r >= M) continue;
#pragma unroll
    for (int j = 0; j < TN; j++) {
      int c = bcol + tc + j;
      float val = acc[i][j];
      if constexpr (EPI == 2) {
        val += resid[(size_t)r * N + c];
      } else {
        if (bias) val += bias[c];
        if constexpr (EPI == 1) val = fmaxf(val, 0.f);
      }
      if constexpr (sizeof(TC) == 2)
        C[(size_t)r * N + c] = (TC)f2bf(val);
      else
        C[(size_t)r * N + c] = (TC)val;
    }
  }
}

// ---------------------------------------------------------------------------
// CSR build
// ---------------------------------------------------------------------------
__global__ void zero_int(int* __restrict__ p, int n) {
  int i = blockIdx.x * blockDim.x + threadIdx.x;
  if (i < n) p[i] = 0;
}

__global__ void histo_kernel(const int* __restrict__ dst, int* __restrict__ deg, int E) {
  int e = blockIdx.x * blockDim.x + threadIdx.x;
  if (e < E) atomicAdd(&deg[dst[e]], 1);
}

__global__ __launch_bounds__(1024) void scan_exclusive(
    const int* __restrict__ deg, int* __restrict__ rowptr, int* __restrict__ cursor, int N) {
  __shared__ int lds[1024];
  __shared__ int base;
  if (threadIdx.x == 0) base = 0;
  __syncthreads();
  for (int start = 0; start < N; start += 1024) {
    int i = start + threadIdx.x;
    int x = (i < N) ? deg[i] : 0;
    lds[threadIdx.x] = x;
    __syncthreads();
    for (int off = 1; off < 1024; off <<= 1) {
      int t = (threadIdx.x >= off) ? lds[threadIdx.x - off] : 0;
      __syncthreads();
      lds[threadIdx.x] += t;
      __syncthreads();
    }
    int excl = lds[threadIdx.x] - x;
    if (i < N) {
      rowptr[i] = base + excl;
      cursor[i] = base + excl;
    }
    __syncthreads();
    if (threadIdx.x == 0) base += lds[1023];
    __syncthreads();
  }
  if (threadIdx.x == 0) rowptr[N] = base;
}

__global__ void scatter_kernel(const int* __restrict__ src, const int* __restrict__ dst,
                               int* __restrict__ cursor, int* __restrict__ esrc, int E) {
  int e = blockIdx.x * blockDim.x + threadIdx.x;
  if (e < E) {
    int d = dst[e];
    int pos = atomicAdd(&cursor[d], 1);
    esrc[pos] = src[e];
  }
}

// ---------------------------------------------------------------------------
// layer_pre (one block): fold attention/gate vectors through the weights.
//   wqv_a[k][o]: o<4 -> sum_d Wq[k, o*128+d]*a_q[o][d] ; o>=4 -> Wv·a_v
//   kk[0..3] = wkw·a_k[h] ; kk[4..7] = wkb·a_k[h]
//   gv[0..127] = wkw@gw ; gv[128..255] = wkb@gw + gb
// ---------------------------------------------------------------------------
__global__ __launch_bounds__(256) void layer_pre(
    const float* __restrict__ wq, const float* __restrict__ wv,
    const float* __restrict__ att_l, const float* __restrict__ wkw,
    const float* __restrict__ wkb, const float* __restrict__ gw,
    const float* __restrict__ gb,
    float* __restrict__ wqv_a, float* __restrict__ kk, float* __restrict__ gv) {
  const int tid = threadIdx.x;
  for (int idx = tid; idx < DD * 8; idx += 256) {
    int k = idx >> 3, o = idx & 7;
    float s = 0.f;
    if (o < 4) {
      const float* w = wq + (size_t)k * QV + o * DD;
      const float* a = att_l + o * 3 * DD + DD;  // a_q
      for (int d = 0; d < DD; d++) s += w[d] * a[d];
    } else {
      int h = o - 4;
      const float* w = wv + (size_t)k * QV + h * DD;
      const float* a = att_l + h * 3 * DD + 2 * DD;  // a_v
      for (int d = 0; d < DD; d++) s += w[d] * a[d];
    }
    wqv_a[idx] = s;
  }
  if (tid < DD) {
    float s1 = 0.f, s0 = 0.f;
    for (int d = 0; d < DD; d++) {
      float g = gw[(size_t)d * DD + tid];
      s1 += wkw[d] * g;
      s0 += wkb[d] * g;
    }
    gv[tid] = s1;
    gv[DD + tid] = s0 + gb[tid];
  }
  if (tid >= 128 && tid < 136) {
    int t = tid - 128;
    int h = t & 3;
    const float* a = att_l + h * 3 * DD;  // a_k
    const float* w = (t < 4) ? wkw : wkb;
    float s = 0.f;
    for (int d = 0; d < DD; d++) s += w[d] * a[d];
    kk[t] = s;
  }
}

// ---------------------------------------------------------------------------
// node_pre2: skq[n,h] = K[n]*kk1[h]+kk0[h] + h[n,:]·wqv_a[:,h]
//            svb[n,h] = h[n,:]·wqv_a[:,4+h].  One wave per node.
// ---------------------------------------------------------------------------
__global__ __launch_bounds__(256) void node_pre2(
    const float* __restrict__ h, const float* __restrict__ Kf,
    const float* __restrict__ wqv_a, const float* __restrict__ kk,
    float* __restrict__ skq, float* __restrict__ svb, int N) {
  __shared__ float W[DD][8];
  __shared__ float kkl[8];
  const int tid = threadIdx.x;
  for (int i = tid; i < DD * 8; i += 256) W[i >> 3][i & 7] = wqv_a[i];
  if (tid < 8) kkl[tid] = kk[tid];
  __syncthreads();
  const int wid = tid >> 6, lane = tid & 63;
  const int n = blockIdx.x * 4 + wid;
  if (n >= N) return;
  const float h0 = h[(size_t)n * DD + lane];
  const float h1 = h[(size_t)n * DD + lane + 64];
  float r[8];
#pragma unroll
  for (int o = 0; o < 8; o++) r[o] = wave_sum(h0 * W[lane][o] + h1 * W[lane + 64][o]);
  if (lane == 0) {
    const float kn = Kf[n];
    *reinterpret_cast<float4*>(skq + (size_t)n * 4) =
        make_float4(r[0] + kn * kkl[0] + kkl[4], r[1] + kn * kkl[1] + kkl[5],
                    r[2] + kn * kkl[2] + kkl[6], r[3] + kn * kkl[3] + kkl[7]);
    *reinterpret_cast<float4*>(svb + (size_t)n * 4) = make_float4(r[4], r[5], r[6], r[7]);
  }
}

// ---------------------------------------------------------------------------
// attn_aggregate: per dst node (one wave): per-head softmax over incoming
// edges + weighted sum of v[src] (bf16) -> agg (bf16). Atomic-free via CSR.
// ---------------------------------------------------------------------------
__global__ __launch_bounds__(256) void attn_aggregate(
    const int* __restrict__ rowptr, const int* __restrict__ esrc,
    const float* __restrict__ skq, const float* __restrict__ svb,
    const unsigned short* __restrict__ v, unsigned short* __restrict__ agg, int N) {
  const int wid = threadIdx.x >> 6;
  const int lane = threadIdx.x & 63;
  const int n = blockIdx.x * 4 + wid;
  if (n >= N) return;
  const int beg = rowptr[n];
  const int end = rowptr[n + 1];
  const float4 kq = *reinterpret_cast<const float4*>(skq + (size_t)n * HH);
  const float kqv[4] = {kq.x, kq.y, kq.z, kq.w};

  float m[HH] = {-3.4e38f, -3.4e38f, -3.4e38f, -3.4e38f};
  for (int i = beg + lane; i < end; i += 64) {
    int s = esrc[i];
    float4 sv = *reinterpret_cast<const float4*>(svb + (size_t)s * HH);
    float svv[4] = {sv.x, sv.y, sv.z, sv.w};
#pragma unroll
    for (int hh = 0; hh < HH; hh++) {
      float sc = kqv[hh] + svv[hh];
      sc = sc > 0.f ? sc : NEG_SLOPE * sc;
      m[hh] = fmaxf(m[hh], sc);
    }
  }
#pragma unroll
  for (int hh = 0; hh < HH; hh++) m[hh] = wave_max(m[hh]);

  float sum[HH] = {0.f, 0.f, 0.f, 0.f};
  for (int i = beg + lane; i < end; i += 64) {
    int s = esrc[i];
    float4 sv = *reinterpret_cast<const float4*>(svb + (size_t)s * HH);
    float svv[4] = {sv.x, sv.y, sv.z, sv.w};
#pragma unroll
    for (int hh = 0; hh < HH; hh++) {
      float sc = kqv[hh] + svv[hh];
      sc = sc > 0.f ? sc : NEG_SLOPE * sc;
      sum[hh] += __expf(sc - m[hh]);
    }
  }
#pragma unroll
  for (int hh = 0; hh < HH; hh++) sum[hh] = wave_sum(sum[hh]);

  float acc[8] = {0.f, 0.f, 0.f, 0.f, 0.f, 0.f, 0.f, 0.f};
  for (int i = beg; i < end; i++) {
    int s = esrc[i];  // uniform across wave
    float4 sv = *reinterpret_cast<const float4*>(svb + (size_t)s * HH);
    float svv[4] = {sv.x, sv.y, sv.z, sv.w};
    float alpha[HH];
#pragma unroll
    for (int hh = 0; hh < HH; hh++) {
      float sc = kqv[hh] + svv[hh];
      sc = sc > 0.f ? sc : NEG_SLOPE * sc;
      alpha[hh] = __expf(sc - m[hh]) / sum[hh];
    }
    const unsigned short* vrow = v + (size_t)s * QV;
#pragma unroll
    for (int jj = 0; jj < 8; jj++) {
      acc[jj] += alpha[jj >> 1] * bf2f(vrow[jj * 64 + lane]);
    }
  }
#pragma unroll
  for (int jj = 0; jj < 8; jj++) agg[(size_t)n * QV + jj * 64 + lane] = f2bf(acc[jj]);
}

// ---------------------------------------------------------------------------
// ln_gate2: LN(outb)*lng+lnb, gate from K[n] (rank-1 folded), relu -> h
// ---------------------------------------------------------------------------
__global__ __launch_bounds__(256) void ln_gate2(
    const float* __restrict__ outb, const float* __restrict__ Kf,
    const float* __restrict__ gv, const float* __restrict__ lng,
    const float* __restrict__ lnb, const float* __restrict__ bl,
    float* __restrict__ h, int N) {
  const int wid = threadIdx.x >> 6;
  const int lane = threadIdx.x & 63;
  const int n = blockIdx.x * 4 + wid;
  if (n >= N) return;
  const float o0 = outb[(size_t)n * DD + lane];
  const float o1 = outb[(size_t)n * DD + lane + 64];
  const float mean = wave_sum(o0 + o1) * (1.f / DD);
  const float c0 = o0 - mean, c1 = o1 - mean;
  const float var = wave_sum(c0 * c0 + c1 * c1) * (1.f / DD);
  const float rs = rsqrtf(var + LN_EPS);
  const float y0 = c0 * rs * lng[lane] + lnb[lane];
  const float y1 = c1 * rs * lng[lane + 64] + lnb[lane + 64];
  const float kn = Kf[n];
  const float g0 = 1.f / (1.f + __expf(-(kn * gv[lane] + gv[DD + lane])));
  const float g1 = 1.f / (1.f + __expf(-(kn * gv[lane + 64] + gv[DD + lane + 64])));
  h[(size_t)n * DD + lane] = fmaxf(y0 * (1.f + g0) + bl[lane], 0.f);
  h[(size_t)n * DD + lane + 64] = fmaxf(y1 * (1.f + g1) + bl[lane + 64], 0.f);
}

// ---------------------------------------------------------------------------
extern "C" void kernel_launch(void* const* d_in, const int* in_sizes, int n_in,
                              void* d_out, int out_size, void* d_ws, size_t ws_size,
                              hipStream_t stream) {
  const float* x = (const float*)d_in[0];
  const int* edge = (const int*)d_in[1];
  const float* Kf = (const float*)d_in[2];
  const float* W_in = (const float*)d_in[3];
  const float* b_in = (const float*)d_in[4];
  const float* Wk_w = (const float*)d_in[5];
  const float* Wk_b = (const float*)d_in[6];
  const float* Wq = (const float*)d_in[7];
  const float* Wv = (const float*)d_in[8];
  const float* att = (const float*)d_in[9];
  const float* Wo = (const float*)d_in[10];
  const float* b_l = (const float*)d_in[11];
  const float* ln_g = (const float*)d_in[12];
  const float* ln_b = (const float*)d_in[13];
  const float* gate_w = (const float*)d_in[14];
  const float* gate_b = (const float*)d_in[15];
  const float* W_out = (const float*)d_in[16];
  const float* b_out = (const float*)d_in[17];
  float* out = (float*)d_out;

  const int* src = edge;
  const int* dst = edge + EE;

  // ---- workspace carve-up (~132 MB total) ----
  char* w = (char*)d_ws;
  auto alloc = [&](size_t bytes) {
    char* p = w;
    w += (bytes + 255) & ~(size_t)255;
    return p;
  };
  float* h = (float*)alloc((size_t)NN * DD * 4);                     // 25.6 MB
  unsigned short* v = (unsigned short*)alloc((size_t)NN * QV * 2);   // 51.2 MB
  unsigned short* agg = (unsigned short*)alloc((size_t)NN * QV * 2); // 51.2 MB
  float* skq = (float*)alloc((size_t)NN * HH * 4);
  float* svb = (float*)alloc((size_t)NN * HH * 4);
  float* wqv_a = (float*)alloc(DD * 8 * 4);
  float* kk = (float*)alloc(8 * 4);
  float* gv = (float*)alloc(2 * DD * 4);
  int* deg = (int*)alloc((size_t)NN * 4);
  int* rowptr = (int*)alloc((size_t)(NN + 1) * 4);
  int* cursor = (int*)alloc((size_t)NN * 4);
  int* esrc = (int*)alloc((size_t)EE * 4);
  float* outb = (float*)v;  // alias: v is dead once attn_aggregate finishes

  dim3 blk(256);

  // ---- CSR build (every call; ws is re-poisoned) ----
  zero_int<<<cdiv(NN, 256), blk, 0, stream>>>(deg, NN);
  histo_kernel<<<cdiv(EE, 256), blk, 0, stream>>>(dst, deg, EE);
  scan_exclusive<<<1, 1024, 0, stream>>>(deg, rowptr, cursor, NN);
  scatter_kernel<<<cdiv(EE, 256), blk, 0, stream>>>(src, dst, cursor, esrc, EE);

  // ---- h = relu(x @ W_in + b_in) ----
  gemm_t<float, float, 1><<<dim3(cdiv(DD, 64), cdiv(NN, 64)), blk, 0, stream>>>(
      x, W_in, b_in, nullptr, h, NN, DD, DD);

  for (int l = 0; l < LL; l++) {
    const float* wkw = Wk_w + (size_t)l * DD;
    const float* wkb = Wk_b + (size_t)l * DD;
    const float* wq = Wq + (size_t)l * DD * QV;
    const float* wv = Wv + (size_t)l * DD * QV;
    const float* att_l = att + (size_t)l * HH * 3 * DD;
    const float* wo = Wo + (size_t)l * QV * DD;
    const float* bl = b_l + (size_t)l * DD;
    const float* lng = ln_g + (size_t)l * DD;
    const float* lnb = ln_b + (size_t)l * DD;
    const float* gw = gate_w + (size_t)l * DD * DD;
    const float* gb = gate_b + (size_t)l * DD;

    layer_pre<<<1, blk, 0, stream>>>(wq, wv, att_l, wkw, wkb, gw, gb, wqv_a, kk, gv);

    // v = h @ wv  (bf16 out)
    gemm_t<float, unsigned short, 0><<<dim3(cdiv(QV, 64), cdiv(NN, 64)), blk, 0, stream>>>(
        h, wv, nullptr, nullptr, v, NN, QV, DD);

    // per-node score components (q folded through a_q; ku rank-1 folded)
    node_pre2<<<cdiv(NN, 4), blk, 0, stream>>>(h, Kf, wqv_a, kk, skq, svb, NN);

    // softmax + aggregation
    attn_aggregate<<<cdiv(NN, 4), blk, 0, stream>>>(rowptr, esrc, skq, svb, v, agg, NN);

    // outb = agg @ wo + h  (writes over dead v region)
    gemm_t<unsigned short, float, 2><<<dim3(cdiv(DD, 64), cdiv(NN, 64)), blk, 0, stream>>>(
        agg, wo, nullptr, h, outb, NN, DD, QV);

    // h = relu(LN(outb)*lng+lnb * (1+sigmoid(K*gv1+gv0)) + bl)
    ln_gate2<<<cdiv(NN, 4), blk, 0, stream>>>(outb, Kf, gv, lng, lnb, bl, h, NN);
  }

  // ---- out = h @ W_out + b_out ----
  gemm_t<float, float, 0><<<dim3(cdiv(64, 64), cdiv(NN, 64)), blk, 0, stream>>>(
      h, W_out, b_out, nullptr, out, NN, 64, DD);
}

// Round 4
// 1075.842 us; speedup vs baseline: 1.3067x; 1.3067x over previous
//
#include <hip/hip_runtime.h>

constexpr int NN = 50000;   // nodes
constexpr int EE = 400000;  // edges
constexpr int DD = 128;     // feature dim
constexpr int HH = 4;       // heads
constexpr int LL = 3;       // layers
constexpr int QV = DD * HH; // 512
constexpr float NEG_SLOPE = 0.01f;
constexpr float LN_EPS = 1e-5f;

static inline int cdiv(int a, int b) { return (a + b - 1) / b; }

#define DEVINL __device__ __forceinline__

typedef __attribute__((ext_vector_type(8))) short bf16x8;
typedef __attribute__((ext_vector_type(8))) unsigned short u16x8;
typedef __attribute__((ext_vector_type(4))) float f32x4;

DEVINL float wave_sum(float v) {
#pragma unroll
  for (int off = 32; off; off >>= 1) v += __shfl_xor(v, off, 64);
  return v;
}
DEVINL float wave_max(float v) {
#pragma unroll
  for (int off = 32; off; off >>= 1) v = fmaxf(v, __shfl_xor(v, off, 64));
  return v;
}

DEVINL float bf2f(unsigned short u) {
  unsigned int t = ((unsigned int)u) << 16;
  float f;
  __builtin_memcpy(&f, &t, 4);
  return f;
}
DEVINL unsigned short f2bf(float f) {
  unsigned int u;
  __builtin_memcpy(&u, &f, 4);
  u = u + 0x7fffu + ((u >> 16) & 1u);  // RNE
  return (unsigned short)(u >> 16);
}

// ---------------------------------------------------------------------------
// MFMA GEMM: C[M,N] = A[M,K] @ B[K,N] where B is supplied TRANSPOSED as
// Bt[N][K] bf16. A is f32 or bf16 (converted to bf16 in staging).
// EPI: 0 = +bias (if non-null), 1 = relu(+bias), 2 = +resid (bf16 resid)
// BM=128, BN=64, BK=128, 256 threads = 4 waves in 2x2 (wr: 64 rows, wc: 32 cols).
// v_mfma_f32_16x16x32_bf16 fragment layouts (m89-verified):
//   A: row=l&15, k=(l>>4)*8+j   B: col=l&15, k=(l>>4)*8+j  (from Bt: contiguous)
//   C/D: col=l&15, row=(l>>4)*4+reg
// ---------------------------------------------------------------------------
template <typename TA, typename TC, int EPI>
__global__ __launch_bounds__(256) void gemm_mfma(
    const TA* __restrict__ A, const unsigned short* __restrict__ Bt,
    const float* __restrict__ bias, const unsigned short* __restrict__ resid,
    TC* __restrict__ C, int M, int N, int K) {
  constexpr int BM = 128, BN = 64, BK = 128, PAD = 8;
  __shared__ unsigned short As[BM][BK + PAD];
  __shared__ unsigned short Bs[BN][BK + PAD];
  const int tid = threadIdx.x;
  const int wave = tid >> 6, lane = tid & 63;
  const int l15 = lane & 15, l4 = lane >> 4;
  const int brow = blockIdx.y * BM, bcol = blockIdx.x * BN;
  const int wr = (wave & 1) * 64;   // wave row offset within tile
  const int wc = (wave >> 1) * 32;  // wave col offset within tile

  f32x4 acc[4][2] = {};

  // staging coords
  const int aRow = tid >> 1;            // 0..127
  const int aCol0 = (tid & 1) * 64;     // 0 or 64
  const int bRow = tid >> 2;            // 0..63
  const int bCol0 = (tid & 3) * 32;     // 0,32,64,96

  for (int k0 = 0; k0 < K; k0 += BK) {
    // ---- stage A (BMxBK bf16) ----
    {
      const int gr = brow + aRow;
      const bool ok = (gr < M);
      if constexpr (sizeof(TA) == 2) {
        const unsigned short* srow = (const unsigned short*)A + (size_t)gr * K + k0 + aCol0;
#pragma unroll
        for (int j = 0; j < 8; j++) {
          u16x8 val = {};
          if (ok) val = *(const u16x8*)(srow + j * 8);
          *(u16x8*)&As[aRow][aCol0 + j * 8] = val;
        }
      } else {
        const float* srow = (const float*)A + (size_t)gr * K + k0 + aCol0;
#pragma unroll
        for (int j = 0; j < 8; j++) {
          u16x8 val = {};
          if (ok) {
            float4 f0 = *(const float4*)(srow + j * 8);
            float4 f1 = *(const float4*)(srow + j * 8 + 4);
            val[0] = f2bf(f0.x); val[1] = f2bf(f0.y); val[2] = f2bf(f0.z); val[3] = f2bf(f0.w);
            val[4] = f2bf(f1.x); val[5] = f2bf(f1.y); val[6] = f2bf(f1.z); val[7] = f2bf(f1.w);
          }
          *(u16x8*)&As[aRow][aCol0 + j * 8] = val;
        }
      }
    }
    // ---- stage B (BNxBK bf16 from Bt[N][K]) ----
    {
      const unsigned short* srow = Bt + (size_t)(bcol + bRow) * K + k0 + bCol0;
#pragma unroll
      for (int j = 0; j < 4; j++) *(u16x8*)&Bs[bRow][bCol0 + j * 8] = *(const u16x8*)(srow + j * 8);
    }
    __syncthreads();
    // ---- compute ----
#pragma unroll
    for (int kk = 0; kk < 4; kk++) {
      bf16x8 a[4], b[2];
#pragma unroll
      for (int m = 0; m < 4; m++) a[m] = *(const bf16x8*)&As[wr + m * 16 + l15][kk * 32 + l4 * 8];
#pragma unroll
      for (int n = 0; n < 2; n++) b[n] = *(const bf16x8*)&Bs[wc + n * 16 + l15][kk * 32 + l4 * 8];
#pragma unroll
      for (int m = 0; m < 4; m++)
#pragma unroll
        for (int n = 0; n < 2; n++)
          acc[m][n] = __builtin_amdgcn_mfma_f32_16x16x32_bf16(a[m], b[n], acc[m][n], 0, 0, 0);
    }
    __syncthreads();
  }

  // ---- epilogue ----
#pragma unroll
  for (int m = 0; m < 4; m++) {
    const int rbase = brow + wr + m * 16 + l4 * 4;
#pragma unroll
    for (int n = 0; n < 2; n++) {
      const int cc = bcol + wc + n * 16 + l15;
#pragma unroll
      for (int j = 0; j < 4; j++) {
        const int rr = rbase + j;
        if (rr >= M) continue;
        float val = acc[m][n][j];
        if constexpr (EPI == 2) {
          val += bf2f(resid[(size_t)rr * N + cc]);
        } else {
          if (bias) val += bias[cc];
          if constexpr (EPI == 1) val = fmaxf(val, 0.f);
        }
        if constexpr (sizeof(TC) == 2)
          C[(size_t)rr * N + cc] = f2bf(val);
        else
          C[(size_t)rr * N + cc] = val;
      }
    }
  }
}

// transpose + f32->bf16: out[n][k] = bf16(in[k][n]); in is [K][N]
__global__ void transp_bf16(const float* __restrict__ in, unsigned short* __restrict__ out,
                            int K, int N) {
  int idx = blockIdx.x * 256 + threadIdx.x;
  if (idx < K * N) {
    int n = idx / K, k = idx - n * K;
    out[idx] = f2bf(in[(size_t)k * N + n]);
  }
}

// ---------------------------------------------------------------------------
// CSR build
// ---------------------------------------------------------------------------
__global__ void zero_int(int* __restrict__ p, int n) {
  int i = blockIdx.x * blockDim.x + threadIdx.x;
  if (i < n) p[i] = 0;
}

__global__ void histo_kernel(const int* __restrict__ dst, int* __restrict__ deg, int E) {
  int e = blockIdx.x * blockDim.x + threadIdx.x;
  if (e < E) atomicAdd(&deg[dst[e]], 1);
}

__global__ __launch_bounds__(1024) void scan_exclusive(
    const int* __restrict__ deg, int* __restrict__ rowptr, int* __restrict__ cursor, int N) {
  __shared__ int lds[1024];
  __shared__ int base;
  if (threadIdx.x == 0) base = 0;
  __syncthreads();
  for (int start = 0; start < N; start += 1024) {
    int i = start + threadIdx.x;
    int x = (i < N) ? deg[i] : 0;
    lds[threadIdx.x] = x;
    __syncthreads();
    for (int off = 1; off < 1024; off <<= 1) {
      int t = (threadIdx.x >= off) ? lds[threadIdx.x - off] : 0;
      __syncthreads();
      lds[threadIdx.x] += t;
      __syncthreads();
    }
    int excl = lds[threadIdx.x] - x;
    if (i < N) {
      rowptr[i] = base + excl;
      cursor[i] = base + excl;
    }
    __syncthreads();
    if (threadIdx.x == 0) base += lds[1023];
    __syncthreads();
  }
  if (threadIdx.x == 0) rowptr[N] = base;
}

__global__ void scatter_kernel(const int* __restrict__ src, const int* __restrict__ dst,
                               int* __restrict__ cursor, int* __restrict__ esrc, int E) {
  int e = blockIdx.x * blockDim.x + threadIdx.x;
  if (e < E) {
    int d = dst[e];
    int pos = atomicAdd(&cursor[d], 1);
    esrc[pos] = src[e];
  }
}

// ---------------------------------------------------------------------------
// layer_pre (one block): fold attention/gate vectors through the weights.
// ---------------------------------------------------------------------------
__global__ __launch_bounds__(256) void layer_pre(
    const float* __restrict__ wq, const float* __restrict__ wv,
    const float* __restrict__ att_l, const float* __restrict__ wkw,
    const float* __restrict__ wkb, const float* __restrict__ gw,
    const float* __restrict__ gb,
    float* __restrict__ wqv_a, float* __restrict__ kk, float* __restrict__ gv) {
  const int tid = threadIdx.x;
  for (int idx = tid; idx < DD * 8; idx += 256) {
    int k = idx >> 3, o = idx & 7;
    float s = 0.f;
    if (o < 4) {
      const float* w = wq + (size_t)k * QV + o * DD;
      const float* a = att_l + o * 3 * DD + DD;  // a_q
      for (int d = 0; d < DD; d++) s += w[d] * a[d];
    } else {
      int h = o - 4;
      const float* w = wv + (size_t)k * QV + h * DD;
      const float* a = att_l + h * 3 * DD + 2 * DD;  // a_v
      for (int d = 0; d < DD; d++) s += w[d] * a[d];
    }
    wqv_a[idx] = s;
  }
  if (tid < DD) {
    float s1 = 0.f, s0 = 0.f;
    for (int d = 0; d < DD; d++) {
      float g = gw[(size_t)d * DD + tid];
      s1 += wkw[d] * g;
      s0 += wkb[d] * g;
    }
    gv[tid] = s1;
    gv[DD + tid] = s0 + gb[tid];
  }
  if (tid >= 128 && tid < 136) {
    int t = tid - 128;
    int h = t & 3;
    const float* a = att_l + h * 3 * DD;  // a_k
    const float* w = (t < 4) ? wkw : wkb;
    float s = 0.f;
    for (int d = 0; d < DD; d++) s += w[d] * a[d];
    kk[t] = s;
  }
}

// ---------------------------------------------------------------------------
// node_pre2: skq[n,h] = K[n]*kk1[h]+kk0[h] + h[n,:]·wqv_a[:,h]
//            svb[n,h] = h[n,:]·wqv_a[:,4+h].  One wave per node. h is bf16.
// ---------------------------------------------------------------------------
__global__ __launch_bounds__(256) void node_pre2(
    const unsigned short* __restrict__ h, const float* __restrict__ Kf,
    const float* __restrict__ wqv_a, const float* __restrict__ kk,
    float* __restrict__ skq, float* __restrict__ svb, int N) {
  __shared__ float W[DD][8];
  __shared__ float kkl[8];
  const int tid = threadIdx.x;
  for (int i = tid; i < DD * 8; i += 256) W[i >> 3][i & 7] = wqv_a[i];
  if (tid < 8) kkl[tid] = kk[tid];
  __syncthreads();
  const int wid = tid >> 6, lane = tid & 63;
  const int n = blockIdx.x * 4 + wid;
  if (n >= N) return;
  const float h0 = bf2f(h[(size_t)n * DD + lane]);
  const float h1 = bf2f(h[(size_t)n * DD + lane + 64]);
  float r[8];
#pragma unroll
  for (int o = 0; o < 8; o++) r[o] = wave_sum(h0 * W[lane][o] + h1 * W[lane + 64][o]);
  if (lane == 0) {
    const float kn = Kf[n];
    *reinterpret_cast<float4*>(skq + (size_t)n * 4) =
        make_float4(r[0] + kn * kkl[0] + kkl[4], r[1] + kn * kkl[1] + kkl[5],
                    r[2] + kn * kkl[2] + kkl[6], r[3] + kn * kkl[3] + kkl[7]);
    *reinterpret_cast<float4*>(svb + (size_t)n * 4) = make_float4(r[4], r[5], r[6], r[7]);
  }
}

// ---------------------------------------------------------------------------
// attn_aggregate: per dst node (one wave): per-head softmax over incoming
// edges + weighted sum of v[src] (bf16) -> agg (bf16). Atomic-free via CSR.
// ---------------------------------------------------------------------------
__global__ __launch_bounds__(256) void attn_aggregate(
    const int* __restrict__ rowptr, const int* __restrict__ esrc,
    const float* __restrict__ skq, const float* __restrict__ svb,
    const unsigned short* __restrict__ v, unsigned short* __restrict__ agg, int N) {
  const int wid = threadIdx.x >> 6;
  const int lane = threadIdx.x & 63;
  const int n = blockIdx.x * 4 + wid;
  if (n >= N) return;
  const int beg = rowptr[n];
  const int end = rowptr[n + 1];
  const float4 kq = *reinterpret_cast<const float4*>(skq + (size_t)n * HH);
  const float kqv[4] = {kq.x, kq.y, kq.z, kq.w};

  float m[HH] = {-3.4e38f, -3.4e38f, -3.4e38f, -3.4e38f};
  for (int i = beg + lane; i < end; i += 64) {
    int s = esrc[i];
    float4 sv = *reinterpret_cast<const float4*>(svb + (size_t)s * HH);
    float svv[4] = {sv.x, sv.y, sv.z, sv.w};
#pragma unroll
    for (int hh = 0; hh < HH; hh++) {
      float sc = kqv[hh] + svv[hh];
      sc = sc > 0.f ? sc : NEG_SLOPE * sc;
      m[hh] = fmaxf(m[hh], sc);
    }
  }
#pragma unroll
  for (int hh = 0; hh < HH; hh++) m[hh] = wave_max(m[hh]);

  float sum[HH] = {0.f, 0.f, 0.f, 0.f};
  for (int i = beg + lane; i < end; i += 64) {
    int s = esrc[i];
    float4 sv = *reinterpret_cast<const float4*>(svb + (size_t)s * HH);
    float svv[4] = {sv.x, sv.y, sv.z, sv.w};
#pragma unroll
    for (int hh = 0; hh < HH; hh++) {
      float sc = kqv[hh] + svv[hh];
      sc = sc > 0.f ? sc : NEG_SLOPE * sc;
      sum[hh] += __expf(sc - m[hh]);
    }
  }
#pragma unroll
  for (int hh = 0; hh < HH; hh++) sum[hh] = wave_sum(sum[hh]);

  float acc[8] = {0.f, 0.f, 0.f, 0.f, 0.f, 0.f, 0.f, 0.f};
  for (int i = beg; i < end; i++) {
    int s = esrc[i];  // uniform across wave
    float4 sv = *reinterpret_cast<const float4*>(svb + (size_t)s * HH);
    float svv[4] = {sv.x, sv.y, sv.z, sv.w};
    float alpha[HH];
#pragma unroll
    for (int hh = 0; hh < HH; hh++) {
      float sc = kqv[hh] + svv[hh];
      sc = sc > 0.f ? sc : NEG_SLOPE * sc;
      alpha[hh] = __expf(sc - m[hh]) / sum[hh];
    }
    const unsigned short* vrow = v + (size_t)s * QV;
#pragma unroll
    for (int jj = 0; jj < 8; jj++) {
      acc[jj] += alpha[jj >> 1] * bf2f(vrow[jj * 64 + lane]);
    }
  }
#pragma unroll
  for (int jj = 0; jj < 8; jj++) agg[(size_t)n * QV + jj * 64 + lane] = f2bf(acc[jj]);
}

// ---------------------------------------------------------------------------
// ln_gate2: LN(outb)*lng+lnb, gate from K[n] (rank-1 folded), relu -> h (bf16)
// ---------------------------------------------------------------------------
__global__ __launch_bounds__(256) void ln_gate2(
    const float* __restrict__ outb, const float* __restrict__ Kf,
    const float* __restrict__ gv, const float* __restrict__ lng,
    const float* __restrict__ lnb, const float* __restrict__ bl,
    unsigned short* __restrict__ h, int N) {
  const int wid = threadIdx.x >> 6;
  const int lane = threadIdx.x & 63;
  const int n = blockIdx.x * 4 + wid;
  if (n >= N) return;
  const float o0 = outb[(size_t)n * DD + lane];
  const float o1 = outb[(size_t)n * DD + lane + 64];
  const float mean = wave_sum(o0 + o1) * (1.f / DD);
  const float c0 = o0 - mean, c1 = o1 - mean;
  const float var = wave_sum(c0 * c0 + c1 * c1) * (1.f / DD);
  const float rs = rsqrtf(var + LN_EPS);
  const float y0 = c0 * rs * lng[lane] + lnb[lane];
  const float y1 = c1 * rs * lng[lane + 64] + lnb[lane + 64];
  const float kn = Kf[n];
  const float g0 = 1.f / (1.f + __expf(-(kn * gv[lane] + gv[DD + lane])));
  const float g1 = 1.f / (1.f + __expf(-(kn * gv[lane + 64] + gv[DD + lane + 64])));
  h[(size_t)n * DD + lane] = f2bf(fmaxf(y0 * (1.f + g0) + bl[lane], 0.f));
  h[(size_t)n * DD + lane + 64] = f2bf(fmaxf(y1 * (1.f + g1) + bl[lane + 64], 0.f));
}

// ---------------------------------------------------------------------------
extern "C" void kernel_launch(void* const* d_in, const int* in_sizes, int n_in,
                              void* d_out, int out_size, void* d_ws, size_t ws_size,
                              hipStream_t stream) {
  const float* x = (const float*)d_in[0];
  const int* edge = (const int*)d_in[1];
  const float* Kf = (const float*)d_in[2];
  const float* W_in = (const float*)d_in[3];
  const float* b_in = (const float*)d_in[4];
  const float* Wk_w = (const float*)d_in[5];
  const float* Wk_b = (const float*)d_in[6];
  const float* Wq = (const float*)d_in[7];
  const float* Wv = (const float*)d_in[8];
  const float* att = (const float*)d_in[9];
  const float* Wo = (const float*)d_in[10];
  const float* b_l = (const float*)d_in[11];
  const float* ln_g = (const float*)d_in[12];
  const float* ln_b = (const float*)d_in[13];
  const float* gate_w = (const float*)d_in[14];
  const float* gate_b = (const float*)d_in[15];
  const float* W_out = (const float*)d_in[16];
  const float* b_out = (const float*)d_in[17];
  float* out = (float*)d_out;

  const int* src = edge;
  const int* dst = edge + EE;

  // ---- workspace carve-up ----
  char* w = (char*)d_ws;
  auto alloc = [&](size_t bytes) {
    char* p = w;
    w += (bytes + 255) & ~(size_t)255;
    return p;
  };
  unsigned short* h = (unsigned short*)alloc((size_t)NN * DD * 2);    // 12.8 MB (bf16)
  unsigned short* v = (unsigned short*)alloc((size_t)NN * QV * 2);    // 51.2 MB
  unsigned short* agg = (unsigned short*)alloc((size_t)NN * QV * 2);  // 51.2 MB
  float* skq = (float*)alloc((size_t)NN * HH * 4);
  float* svb = (float*)alloc((size_t)NN * HH * 4);
  float* wqv_a = (float*)alloc(DD * 8 * 4);
  float* kk = (float*)alloc(8 * 4);
  float* gv = (float*)alloc(2 * DD * 4);
  int* deg = (int*)alloc((size_t)NN * 4);
  int* rowptr = (int*)alloc((size_t)(NN + 1) * 4);
  int* cursor = (int*)alloc((size_t)NN * 4);
  int* esrc = (int*)alloc((size_t)EE * 4);
  unsigned short* Wint = (unsigned short*)alloc((size_t)DD * DD * 2);     // [128][128]
  unsigned short* Woutt = (unsigned short*)alloc((size_t)64 * DD * 2);    // [64][128]
  unsigned short* Wvt[LL];
  unsigned short* Wot[LL];
  for (int l = 0; l < LL; l++) {
    Wvt[l] = (unsigned short*)alloc((size_t)QV * DD * 2);  // [512][128]
    Wot[l] = (unsigned short*)alloc((size_t)DD * QV * 2);  // [128][512]
  }
  float* outb = (float*)v;  // alias: v is dead once attn_aggregate finishes

  dim3 blk(256);

  // ---- CSR build (every call; ws is re-poisoned) ----
  zero_int<<<cdiv(NN, 256), blk, 0, stream>>>(deg, NN);
  histo_kernel<<<cdiv(EE, 256), blk, 0, stream>>>(dst, deg, EE);
  scan_exclusive<<<1, 1024, 0, stream>>>(deg, rowptr, cursor, NN);
  scatter_kernel<<<cdiv(EE, 256), blk, 0, stream>>>(src, dst, cursor, esrc, EE);

  // ---- weight transposes (bf16, [N][K] layout) ----
  transp_bf16<<<cdiv(DD * DD, 256), blk, 0, stream>>>(W_in, Wint, DD, DD);
  transp_bf16<<<cdiv(DD * 64, 256), blk, 0, stream>>>(W_out, Woutt, DD, 64);
  for (int l = 0; l < LL; l++) {
    transp_bf16<<<cdiv(DD * QV, 256), blk, 0, stream>>>(Wv + (size_t)l * DD * QV, Wvt[l], DD, QV);
    transp_bf16<<<cdiv(QV * DD, 256), blk, 0, stream>>>(Wo + (size_t)l * QV * DD, Wot[l], QV, DD);
  }

  // ---- h = relu(x @ W_in + b_in)  (bf16 out) ----
  gemm_mfma<float, unsigned short, 1><<<dim3(DD / 64, cdiv(NN, 128)), blk, 0, stream>>>(
      x, Wint, b_in, nullptr, h, NN, DD, DD);

  for (int l = 0; l < LL; l++) {
    const float* wkw = Wk_w + (size_t)l * DD;
    const float* wkb = Wk_b + (size_t)l * DD;
    const float* wq = Wq + (size_t)l * DD * QV;
    const float* wv = Wv + (size_t)l * DD * QV;
    const float* att_l = att + (size_t)l * HH * 3 * DD;
    const float* bl = b_l + (size_t)l * DD;
    const float* lng = ln_g + (size_t)l * DD;
    const float* lnb = ln_b + (size_t)l * DD;
    const float* gw = gate_w + (size_t)l * DD * DD;
    const float* gb = gate_b + (size_t)l * DD;

    layer_pre<<<1, blk, 0, stream>>>(wq, wv, att_l, wkw, wkb, gw, gb, wqv_a, kk, gv);

    // v = h @ wv  (bf16 out)
    gemm_mfma<unsigned short, unsigned short, 0><<<dim3(QV / 64, cdiv(NN, 128)), blk, 0, stream>>>(
        h, Wvt[l], nullptr, nullptr, v, NN, QV, DD);

    // per-node score components (q folded through a_q; ku rank-1 folded)
    node_pre2<<<cdiv(NN, 4), blk, 0, stream>>>(h, Kf, wqv_a, kk, skq, svb, NN);

    // softmax + aggregation
    attn_aggregate<<<cdiv(NN, 4), blk, 0, stream>>>(rowptr, esrc, skq, svb, v, agg, NN);

    // outb = agg @ wo + h  (f32 out over dead v region)
    gemm_mfma<unsigned short, float, 2><<<dim3(DD / 64, cdiv(NN, 128)), blk, 0, stream>>>(
        agg, Wot[l], nullptr, h, outb, NN, DD, QV);

    // h = relu(LN(outb)*lng+lnb * (1+sigmoid(K*gv1+gv0)) + bl)  (bf16 out)
    ln_gate2<<<cdiv(NN, 4), blk, 0, stream>>>(outb, Kf, gv, lng, lnb, bl, h, NN);
  }

  // ---- out = h @ W_out + b_out  (f32) ----
  gemm_mfma<unsigned short, float, 0><<<dim3(64 / 64, cdiv(NN, 128)), blk, 0, stream>>>(
      h, Woutt, b_out, nullptr, out, NN, 64, DD);
}

// Round 6
// 835.470 us; speedup vs baseline: 1.6826x; 1.2877x over previous
//
#include <hip/hip_runtime.h>

constexpr int NN = 50000;   // nodes
constexpr int EE = 400000;  // edges
constexpr int DD = 128;     // feature dim
constexpr int HH = 4;       // heads
constexpr int LL = 3;       // layers
constexpr int QV = DD * HH; // 512
constexpr float NEG_SLOPE = 0.01f;
constexpr float LN_EPS = 1e-5f;

static inline int cdiv(int a, int b) { return (a + b - 1) / b; }

#define DEVINL __device__ __forceinline__

typedef __attribute__((ext_vector_type(8))) short bf16x8;
typedef __attribute__((ext_vector_type(8))) unsigned short u16x8;
typedef __attribute__((ext_vector_type(4))) float f32x4;

DEVINL float wave_sum(float v) {
#pragma unroll
  for (int off = 32; off; off >>= 1) v += __shfl_xor(v, off, 64);
  return v;
}

DEVINL float bf2f(unsigned short u) {
  unsigned int t = ((unsigned int)u) << 16;
  float f;
  __builtin_memcpy(&f, &t, 4);
  return f;
}
DEVINL unsigned short f2bf(float f) {
  unsigned int u;
  __builtin_memcpy(&u, &f, 4);
  u = u + 0x7fffu + ((u >> 16) & 1u);  // RNE
  return (unsigned short)(u >> 16);
}

// ---------------------------------------------------------------------------
// MFMA GEMM: C[M,N] = A[M,K] @ B[K,N], B supplied TRANSPOSED as Bt[N][K] bf16.
// A f32 or bf16. EPI: 0=+bias, 1=relu(+bias), 2=+resid(bf16)
// BM=128, BN=64, BK=128, 256 threads = 4 waves (2x2).
// ---------------------------------------------------------------------------
template <typename TA, typename TC, int EPI>
__global__ __launch_bounds__(256) void gemm_mfma(
    const TA* __restrict__ A, const unsigned short* __restrict__ Bt,
    const float* __restrict__ bias, const unsigned short* __restrict__ resid,
    TC* __restrict__ C, int M, int N, int K) {
  constexpr int BM = 128, BN = 64, BK = 128, PAD = 8;
  __shared__ unsigned short As[BM][BK + PAD];
  __shared__ unsigned short Bs[BN][BK + PAD];
  const int tid = threadIdx.x;
  const int wave = tid >> 6, lane = tid & 63;
  const int l15 = lane & 15, l4 = lane >> 4;
  const int brow = blockIdx.y * BM, bcol = blockIdx.x * BN;
  const int wr = (wave & 1) * 64;
  const int wc = (wave >> 1) * 32;

  f32x4 acc[4][2] = {};

  const int aRow = tid >> 1;
  const int aCol0 = (tid & 1) * 64;
  const int bRow = tid >> 2;
  const int bCol0 = (tid & 3) * 32;

  for (int k0 = 0; k0 < K; k0 += BK) {
    {
      const int gr = brow + aRow;
      const bool ok = (gr < M);
      if constexpr (sizeof(TA) == 2) {
        const unsigned short* srow = (const unsigned short*)A + (size_t)gr * K + k0 + aCol0;
#pragma unroll
        for (int j = 0; j < 8; j++) {
          u16x8 val = {};
          if (ok) val = *(const u16x8*)(srow + j * 8);
          *(u16x8*)&As[aRow][aCol0 + j * 8] = val;
        }
      } else {
        const float* srow = (const float*)A + (size_t)gr * K + k0 + aCol0;
#pragma unroll
        for (int j = 0; j < 8; j++) {
          u16x8 val = {};
          if (ok) {
            float4 f0 = *(const float4*)(srow + j * 8);
            float4 f1 = *(const float4*)(srow + j * 8 + 4);
            val[0] = f2bf(f0.x); val[1] = f2bf(f0.y); val[2] = f2bf(f0.z); val[3] = f2bf(f0.w);
            val[4] = f2bf(f1.x); val[5] = f2bf(f1.y); val[6] = f2bf(f1.z); val[7] = f2bf(f1.w);
          }
          *(u16x8*)&As[aRow][aCol0 + j * 8] = val;
        }
      }
    }
    {
      const unsigned short* srow = Bt + (size_t)(bcol + bRow) * K + k0 + bCol0;
#pragma unroll
      for (int j = 0; j < 4; j++) *(u16x8*)&Bs[bRow][bCol0 + j * 8] = *(const u16x8*)(srow + j * 8);
    }
    __syncthreads();
#pragma unroll
    for (int kk = 0; kk < 4; kk++) {
      bf16x8 a[4], b[2];
#pragma unroll
      for (int m = 0; m < 4; m++) a[m] = *(const bf16x8*)&As[wr + m * 16 + l15][kk * 32 + l4 * 8];
#pragma unroll
      for (int n = 0; n < 2; n++) b[n] = *(const bf16x8*)&Bs[wc + n * 16 + l15][kk * 32 + l4 * 8];
#pragma unroll
      for (int m = 0; m < 4; m++)
#pragma unroll
        for (int n = 0; n < 2; n++)
          acc[m][n] = __builtin_amdgcn_mfma_f32_16x16x32_bf16(a[m], b[n], acc[m][n], 0, 0, 0);
    }
    __syncthreads();
  }

#pragma unroll
  for (int m = 0; m < 4; m++) {
    const int rbase = brow + wr + m * 16 + l4 * 4;
#pragma unroll
    for (int n = 0; n < 2; n++) {
      const int cc = bcol + wc + n * 16 + l15;
#pragma unroll
      for (int j = 0; j < 4; j++) {
        const int rr = rbase + j;
        if (rr >= M) continue;
        float val = acc[m][n][j];
        if constexpr (EPI == 2) {
          val += bf2f(resid[(size_t)rr * N + cc]);
        } else {
          if (bias) val += bias[cc];
          if constexpr (EPI == 1) val = fmaxf(val, 0.f);
        }
        if constexpr (sizeof(TC) == 2)
          C[(size_t)rr * N + cc] = f2bf(val);
        else
          C[(size_t)rr * N + cc] = val;
      }
    }
  }
}

// transpose + f32->bf16: out[n][k] = bf16(in[k][n]); in is [K][N]
__global__ void transp_bf16(const float* __restrict__ in, unsigned short* __restrict__ out,
                            int K, int N) {
  int idx = blockIdx.x * 256 + threadIdx.x;
  if (idx < K * N) {
    int n = idx / K, k = idx - n * K;
    out[idx] = f2bf(in[(size_t)k * N + n]);
  }
}

// ---------------------------------------------------------------------------
// CSR build (multi-block scan)
// ---------------------------------------------------------------------------
__global__ void zero_int(int* __restrict__ p, int n) {
  int i = blockIdx.x * blockDim.x + threadIdx.x;
  if (i < n) p[i] = 0;
}

__global__ void histo_kernel(const int* __restrict__ dst, int* __restrict__ deg, int E) {
  int e = blockIdx.x * blockDim.x + threadIdx.x;
  if (e < E) atomicAdd(&deg[dst[e]], 1);
}

// per-block inclusive scan of 1024-chunks; writes exclusive (no base) + blocksum
__global__ __launch_bounds__(1024) void scan_blocks(
    const int* __restrict__ deg, int* __restrict__ rowptr, int* __restrict__ blocksum, int N) {
  __shared__ int lds[1024];
  const int tid = threadIdx.x;
  const int i = blockIdx.x * 1024 + tid;
  int x = (i < N) ? deg[i] : 0;
  lds[tid] = x;
  __syncthreads();
  for (int off = 1; off < 1024; off <<= 1) {
    int t = (tid >= off) ? lds[tid - off] : 0;
    __syncthreads();
    lds[tid] += t;
    __syncthreads();
  }
  if (i < N) rowptr[i] = lds[tid] - x;
  if (tid == 1023) blocksum[blockIdx.x] = lds[1023];
}

__global__ void scan_sums(int* __restrict__ blocksum, int* __restrict__ rowptr, int NB, int N) {
  if (threadIdx.x == 0 && blockIdx.x == 0) {
    int run = 0;
    for (int b = 0; b < NB; b++) {
      int t = blocksum[b];
      blocksum[b] = run;
      run += t;
    }
    rowptr[N] = run;
  }
}

__global__ void scan_apply(int* __restrict__ rowptr, int* __restrict__ cursor,
                           const int* __restrict__ blocksum, int N) {
  int i = blockIdx.x * blockDim.x + threadIdx.x;
  if (i < N) {
    int val = rowptr[i] + blocksum[i >> 10];
    rowptr[i] = val;
    cursor[i] = val;
  }
}

__global__ void scatter_kernel(const int* __restrict__ src, const int* __restrict__ dst,
                               int* __restrict__ cursor, int* __restrict__ esrc, int E) {
  int e = blockIdx.x * blockDim.x + threadIdx.x;
  if (e < E) {
    int d = dst[e];
    int pos = atomicAdd(&cursor[d], 1);
    esrc[pos] = src[e];
  }
}

// ---------------------------------------------------------------------------
// layer_pre, 5 blocks: blocks 0-3 fold a_q/a_v through Wq/Wv; block 4: gate+kk.
//   wqv_a[k][o]: o<4 -> Wq[k, o*128+:]·a_q[o] ; o>=4 -> Wv[k, h*128+:]·a_v[h]
//   kk[0..3] = wkw·a_k[h] ; kk[4..7] = wkb·a_k[h]
//   gv[0..127] = wkw@gw ; gv[128..255] = wkb@gw + gb
// ---------------------------------------------------------------------------
__global__ __launch_bounds__(256) void layer_pre(
    const float* __restrict__ wq, const float* __restrict__ wv,
    const float* __restrict__ att_l, const float* __restrict__ wkw,
    const float* __restrict__ wkb, const float* __restrict__ gw,
    const float* __restrict__ gb,
    float* __restrict__ wqv_a, float* __restrict__ kk, float* __restrict__ gv) {
  const int tid = threadIdx.x;
  const int blk = blockIdx.x;
  if (blk < 4) {
    int idx = blk * 256 + tid;
    int k = idx >> 3, o = idx & 7;
    float s = 0.f;
    if (o < 4) {
      const float* w = wq + (size_t)k * QV + o * DD;
      const float* a = att_l + o * 3 * DD + DD;  // a_q
      for (int d = 0; d < DD; d++) s += w[d] * a[d];
    } else {
      int h = o - 4;
      const float* w = wv + (size_t)k * QV + h * DD;
      const float* a = att_l + h * 3 * DD + 2 * DD;  // a_v
      for (int d = 0; d < DD; d++) s += w[d] * a[d];
    }
    wqv_a[idx] = s;
  } else {
    if (tid < DD) {
      float s1 = 0.f, s0 = 0.f;
      for (int d = 0; d < DD; d++) {
        float g = gw[(size_t)d * DD + tid];
        s1 += wkw[d] * g;
        s0 += wkb[d] * g;
      }
      gv[tid] = s1;
      gv[DD + tid] = s0 + gb[tid];
    }
    if (tid >= 128 && tid < 136) {
      int t = tid - 128;
      int h = t & 3;
      const float* a = att_l + h * 3 * DD;  // a_k
      const float* w = (t < 4) ? wkw : wkb;
      float s = 0.f;
      for (int d = 0; d < DD; d++) s += w[d] * a[d];
      kk[t] = s;
    }
  }
}

// ---------------------------------------------------------------------------
// node_pre2: skq[n,h] = K[n]*kk1[h]+kk0[h] + h[n,:]·wqv_a[:,h]
//            svb[n,h] = h[n,:]·wqv_a[:,4+h].  One wave per node. h is bf16.
// ---------------------------------------------------------------------------
__global__ __launch_bounds__(256) void node_pre2(
    const unsigned short* __restrict__ h, const float* __restrict__ Kf,
    const float* __restrict__ wqv_a, const float* __restrict__ kk,
    float* __restrict__ skq, float* __restrict__ svb, int N) {
  __shared__ float W[DD][8];
  __shared__ float kkl[8];
  const int tid = threadIdx.x;
  for (int i = tid; i < DD * 8; i += 256) W[i >> 3][i & 7] = wqv_a[i];
  if (tid < 8) kkl[tid] = kk[tid];
  __syncthreads();
  const int wid = tid >> 6, lane = tid & 63;
  const int n = blockIdx.x * 4 + wid;
  if (n >= N) return;
  const float h0 = bf2f(h[(size_t)n * DD + lane]);
  const float h1 = bf2f(h[(size_t)n * DD + lane + 64]);
  float r[8];
#pragma unroll
  for (int o = 0; o < 8; o++) r[o] = wave_sum(h0 * W[lane][o] + h1 * W[lane + 64][o]);
  if (lane == 0) {
    const float kn = Kf[n];
    *reinterpret_cast<float4*>(skq + (size_t)n * 4) =
        make_float4(r[0] + kn * kkl[0] + kkl[4], r[1] + kn * kkl[1] + kkl[5],
                    r[2] + kn * kkl[2] + kkl[6], r[3] + kn * kkl[3] + kkl[7]);
    *reinterpret_cast<float4*>(svb + (size_t)n * 4) = make_float4(r[4], r[5], r[6], r[7]);
  }
}

// ---------------------------------------------------------------------------
// attn_aggregate: single pass per dst node. Lane owns cols [lane*8, lane*8+8);
// its head = lane>>4. alpha normalization applied once at the end (softmax is
// shift-invariant; scores are O(1), clamped at 60 for safety).
// ---------------------------------------------------------------------------
__global__ __launch_bounds__(256) void attn_aggregate(
    const int* __restrict__ rowptr, const int* __restrict__ esrc,
    const float* __restrict__ skq, const float* __restrict__ svb,
    const unsigned short* __restrict__ v, unsigned short* __restrict__ agg, int N) {
  const int wid = threadIdx.x >> 6;
  const int lane = threadIdx.x & 63;
  const int n = blockIdx.x * 4 + wid;
  if (n >= N) return;
  const int beg = rowptr[n];
  const int end = rowptr[n + 1];
  const int hh = lane >> 4;  // this lane's head
  const float kq = skq[(size_t)n * HH + hh];

  float sumw = 0.f;
  float acc[8] = {0.f, 0.f, 0.f, 0.f, 0.f, 0.f, 0.f, 0.f};
  for (int i = beg; i < end; i++) {
    const int s = esrc[i];  // uniform across wave
    float sc = kq + svb[(size_t)s * HH + hh];
    sc = sc > 0.f ? sc : NEG_SLOPE * sc;
    const float ex = __expf(fminf(sc, 60.f));
    sumw += ex;
    const u16x8 vr = *(const u16x8*)(v + (size_t)s * QV + lane * 8);
#pragma unroll
    for (int j = 0; j < 8; j++) acc[j] += ex * bf2f(vr[j]);
  }
  const float inv = (end > beg) ? 1.f / sumw : 0.f;
  u16x8 outv;
#pragma unroll
  for (int j = 0; j < 8; j++) outv[j] = f2bf(acc[j] * inv);
  *(u16x8*)(agg + (size_t)n * QV + lane * 8) = outv;
}

// ---------------------------------------------------------------------------
// ln_gate2: LN(outb)*lng+lnb, gate from K[n] (rank-1 folded), relu -> h (bf16)
// ---------------------------------------------------------------------------
__global__ __launch_bounds__(256) void ln_gate2(
    const float* __restrict__ outb, const float* __restrict__ Kf,
    const float* __restrict__ gv, const float* __restrict__ lng,
    const float* __restrict__ lnb, const float* __restrict__ bl,
    unsigned short* __restrict__ h, int N) {
  const int wid = threadIdx.x >> 6;
  const int lane = threadIdx.x & 63;
  const int n = blockIdx.x * 4 + wid;
  if (n >= N) return;
  const float o0 = outb[(size_t)n * DD + lane];
  const float o1 = outb[(size_t)n * DD + lane + 64];
  const float mean = wave_sum(o0 + o1) * (1.f / DD);
  const float c0 = o0 - mean, c1 = o1 - mean;
  const float var = wave_sum(c0 * c0 + c1 * c1) * (1.f / DD);
  const float rs = rsqrtf(var + LN_EPS);
  const float y0 = c0 * rs * lng[lane] + lnb[lane];
  const float y1 = c1 * rs * lng[lane + 64] + lnb[lane + 64];
  const float kn = Kf[n];
  const float g0 = 1.f / (1.f + __expf(-(kn * gv[lane] + gv[DD + lane])));
  const float g1 = 1.f / (1.f + __expf(-(kn * gv[lane + 64] + gv[DD + lane + 64])));
  h[(size_t)n * DD + lane] = f2bf(fmaxf(y0 * (1.f + g0) + bl[lane], 0.f));
  h[(size_t)n * DD + lane + 64] = f2bf(fmaxf(y1 * (1.f + g1) + bl[lane + 64], 0.f));
}

// ---------------------------------------------------------------------------
extern "C" void kernel_launch(void* const* d_in, const int* in_sizes, int n_in,
                              void* d_out, int out_size, void* d_ws, size_t ws_size,
                              hipStream_t stream) {
  const float* x = (const float*)d_in[0];
  const int* edge = (const int*)d_in[1];
  const float* Kf = (const float*)d_in[2];
  const float* W_in = (const float*)d_in[3];
  const float* b_in = (const float*)d_in[4];
  const float* Wk_w = (const float*)d_in[5];
  const float* Wk_b = (const float*)d_in[6];
  const float* Wq = (const float*)d_in[7];
  const float* Wv = (const float*)d_in[8];
  const float* att = (const float*)d_in[9];
  const float* Wo = (const float*)d_in[10];
  const float* b_l = (const float*)d_in[11];
  const float* ln_g = (const float*)d_in[12];
  const float* ln_b = (const float*)d_in[13];
  const float* gate_w = (const float*)d_in[14];
  const float* gate_b = (const float*)d_in[15];
  const float* W_out = (const float*)d_in[16];
  const float* b_out = (const float*)d_in[17];
  float* out = (float*)d_out;

  const int* src = edge;
  const int* dst = edge + EE;

  // ---- workspace carve-up ----
  char* w = (char*)d_ws;
  auto alloc = [&](size_t bytes) {
    char* p = w;
    w += (bytes + 255) & ~(size_t)255;
    return p;
  };
  unsigned short* h = (unsigned short*)alloc((size_t)NN * DD * 2);
  unsigned short* v = (unsigned short*)alloc((size_t)NN * QV * 2);
  unsigned short* agg = (unsigned short*)alloc((size_t)NN * QV * 2);
  float* skq = (float*)alloc((size_t)NN * HH * 4);
  float* svb = (float*)alloc((size_t)NN * HH * 4);
  float* wqv_a = (float*)alloc(DD * 8 * 4);
  float* kk = (float*)alloc(8 * 4);
  float* gv = (float*)alloc(2 * DD * 4);
  int* deg = (int*)alloc((size_t)NN * 4);
  int* rowptr = (int*)alloc((size_t)(NN + 1) * 4);
  int* cursor = (int*)alloc((size_t)NN * 4);
  int* esrc = (int*)alloc((size_t)EE * 4);
  int* blocksum = (int*)alloc((size_t)64 * 4);
  unsigned short* Wint = (unsigned short*)alloc((size_t)DD * DD * 2);
  unsigned short* Woutt = (unsigned short*)alloc((size_t)64 * DD * 2);
  unsigned short* Wvt[LL];
  unsigned short* Wot[LL];
  for (int l = 0; l < LL; l++) {
    Wvt[l] = (unsigned short*)alloc((size_t)QV * DD * 2);
    Wot[l] = (unsigned short*)alloc((size_t)DD * QV * 2);
  }
  float* outb = (float*)v;  // alias: v dead after attn_aggregate

  dim3 blk(256);
  const int NB = cdiv(NN, 1024);

  // ---- CSR build ----
  zero_int<<<cdiv(NN, 256), blk, 0, stream>>>(deg, NN);
  histo_kernel<<<cdiv(EE, 256), blk, 0, stream>>>(dst, deg, EE);
  scan_blocks<<<NB, 1024, 0, stream>>>(deg, rowptr, blocksum, NN);
  scan_sums<<<1, 64, 0, stream>>>(blocksum, rowptr, NB, NN);
  scan_apply<<<cdiv(NN, 256), blk, 0, stream>>>(rowptr, cursor, blocksum, NN);
  scatter_kernel<<<cdiv(EE, 256), blk, 0, stream>>>(src, dst, cursor, esrc, EE);

  // ---- weight transposes (bf16, [N][K] layout) ----
  transp_bf16<<<cdiv(DD * DD, 256), blk, 0, stream>>>(W_in, Wint, DD, DD);
  transp_bf16<<<cdiv(DD * 64, 256), blk, 0, stream>>>(W_out, Woutt, DD, 64);
  for (int l = 0; l < LL; l++) {
    transp_bf16<<<cdiv(DD * QV, 256), blk, 0, stream>>>(Wv + (size_t)l * DD * QV, Wvt[l], DD, QV);
    transp_bf16<<<cdiv(QV * DD, 256), blk, 0, stream>>>(Wo + (size_t)l * QV * DD, Wot[l], QV, DD);
  }

  // ---- h = relu(x @ W_in + b_in)  (bf16 out) ----
  gemm_mfma<float, unsigned short, 1><<<dim3(DD / 64, cdiv(NN, 128)), blk, 0, stream>>>(
      x, Wint, b_in, nullptr, h, NN, DD, DD);

  for (int l = 0; l < LL; l++) {
    const float* wkw = Wk_w + (size_t)l * DD;
    const float* wkb = Wk_b + (size_t)l * DD;
    const float* wq = Wq + (size_t)l * DD * QV;
    const float* wv = Wv + (size_t)l * DD * QV;
    const float* att_l = att + (size_t)l * HH * 3 * DD;
    const float* bl = b_l + (size_t)l * DD;
    const float* lng = ln_g + (size_t)l * DD;
    const float* lnb = ln_b + (size_t)l * DD;
    const float* gw = gate_w + (size_t)l * DD * DD;
    const float* gb = gate_b + (size_t)l * DD;

    layer_pre<<<5, blk, 0, stream>>>(wq, wv, att_l, wkw, wkb, gw, gb, wqv_a, kk, gv);

    // v = h @ wv  (bf16 out)
    gemm_mfma<unsigned short, unsigned short, 0><<<dim3(QV / 64, cdiv(NN, 128)), blk, 0, stream>>>(
        h, Wvt[l], nullptr, nullptr, v, NN, QV, DD);

    // per-node score components
    node_pre2<<<cdiv(NN, 4), blk, 0, stream>>>(h, Kf, wqv_a, kk, skq, svb, NN);

    // single-pass softmax + aggregation
    attn_aggregate<<<cdiv(NN, 4), blk, 0, stream>>>(rowptr, esrc, skq, svb, v, agg, NN);

    // outb = agg @ wo + h  (f32 out over dead v region)
    gemm_mfma<unsigned short, float, 2><<<dim3(DD / 64, cdiv(NN, 128)), blk, 0, stream>>>(
        agg, Wot[l], nullptr, h, outb, NN, DD, QV);

    // h = relu(LN(outb)*lng+lnb * (1+sigmoid(K*gv1+gv0)) + bl)  (bf16 out)
    ln_gate2<<<cdiv(NN, 4), blk, 0, stream>>>(outb, Kf, gv, lng, lnb, bl, h, NN);
  }

  // ---- out = h @ W_out + b_out  (f32) ----
  gemm_mfma<unsigned short, float, 0><<<dim3(64 / 64, cdiv(NN, 128)), blk, 0, stream>>>(
      h, Woutt, b_out, nullptr, out, NN, 64, DD);
}

// Round 7
// 742.147 us; speedup vs baseline: 1.8942x; 1.1257x over previous
//
#include <hip/hip_runtime.h>

constexpr int NN = 50000;   // nodes
constexpr int EE = 400000;  // edges
constexpr int DD = 128;     // feature dim
constexpr int HH = 4;       // heads
constexpr int LL = 3;       // layers
constexpr int QV = DD * HH; // 512
constexpr float NEG_SLOPE = 0.01f;
constexpr float LN_EPS = 1e-5f;

static inline int cdiv(int a, int b) { return (a + b - 1) / b; }

#define DEVINL __device__ __forceinline__

typedef __attribute__((ext_vector_type(8))) short bf16x8;
typedef __attribute__((ext_vector_type(8))) unsigned short u16x8;
typedef __attribute__((ext_vector_type(4))) float f32x4;

DEVINL float wave_sum(float v) {
#pragma unroll
  for (int off = 32; off; off >>= 1) v += __shfl_xor(v, off, 64);
  return v;
}

DEVINL float bf2f(unsigned short u) {
  unsigned int t = ((unsigned int)u) << 16;
  float f;
  __builtin_memcpy(&f, &t, 4);
  return f;
}
DEVINL unsigned short f2bf(float f) {
  unsigned int u;
  __builtin_memcpy(&u, &f, 4);
  u = u + 0x7fffu + ((u >> 16) & 1u);  // RNE
  return (unsigned short)(u >> 16);
}

// ---------------------------------------------------------------------------
// MFMA GEMM: C[M,N] = A[M,K] @ B[K,N], B supplied TRANSPOSED as Bt[N][K] bf16.
// A f32 or bf16. EPI: 0=+bias(if non-null), 1=relu(+bias).
// BM=128, BK=128, BN in {64,128}. 256 threads = 4 waves; each wave computes
// 64 x (BN/2). v_mfma_f32_16x16x32_bf16 (m89-verified layouts).
// ---------------------------------------------------------------------------
template <typename TA, typename TC, int EPI, int BN>
__global__ __launch_bounds__(256) void gemm_mfma(
    const TA* __restrict__ A, const unsigned short* __restrict__ Bt,
    const float* __restrict__ bias, TC* __restrict__ C, int M, int N, int K) {
  constexpr int BM = 128, BK = 128, PAD = 8;
  constexpr int NF = BN / 32;  // 4 for BN=128, 2 for BN=64
  __shared__ unsigned short As[BM][BK + PAD];
  __shared__ unsigned short Bs[BN][BK + PAD];
  const int tid = threadIdx.x;
  const int wave = tid >> 6, lane = tid & 63;
  const int l15 = lane & 15, l4 = lane >> 4;
  const int brow = blockIdx.y * BM, bcol = blockIdx.x * BN;
  const int wr = (wave & 1) * 64;
  const int wc = (wave >> 1) * (BN / 2);

  f32x4 acc[4][NF] = {};
  const int aRow = tid >> 1;
  const int aCol0 = (tid & 1) * 64;

  for (int k0 = 0; k0 < K; k0 += BK) {
    {
      const int gr = brow + aRow;
      const bool ok = (gr < M);
      if constexpr (sizeof(TA) == 2) {
        const unsigned short* srow = (const unsigned short*)A + (size_t)gr * K + k0 + aCol0;
#pragma unroll
        for (int j = 0; j < 8; j++) {
          u16x8 val = {};
          if (ok) val = *(const u16x8*)(srow + j * 8);
          *(u16x8*)&As[aRow][aCol0 + j * 8] = val;
        }
      } else {
        const float* srow = (const float*)A + (size_t)gr * K + k0 + aCol0;
#pragma unroll
        for (int j = 0; j < 8; j++) {
          u16x8 val = {};
          if (ok) {
            float4 f0 = *(const float4*)(srow + j * 8);
            float4 f1 = *(const float4*)(srow + j * 8 + 4);
            val[0] = f2bf(f0.x); val[1] = f2bf(f0.y); val[2] = f2bf(f0.z); val[3] = f2bf(f0.w);
            val[4] = f2bf(f1.x); val[5] = f2bf(f1.y); val[6] = f2bf(f1.z); val[7] = f2bf(f1.w);
          }
          *(u16x8*)&As[aRow][aCol0 + j * 8] = val;
        }
      }
    }
    if constexpr (BN == 128) {
      const unsigned short* srow = Bt + (size_t)(bcol + aRow) * K + k0 + aCol0;
#pragma unroll
      for (int j = 0; j < 8; j++) *(u16x8*)&Bs[aRow][aCol0 + j * 8] = *(const u16x8*)(srow + j * 8);
    } else {
      const int bRow = tid >> 2, bCol0 = (tid & 3) * 32;
      const unsigned short* srow = Bt + (size_t)(bcol + bRow) * K + k0 + bCol0;
#pragma unroll
      for (int j = 0; j < 4; j++) *(u16x8*)&Bs[bRow][bCol0 + j * 8] = *(const u16x8*)(srow + j * 8);
    }
    __syncthreads();
#pragma unroll
    for (int kk = 0; kk < 4; kk++) {
      bf16x8 a[4], b[NF];
#pragma unroll
      for (int m = 0; m < 4; m++) a[m] = *(const bf16x8*)&As[wr + m * 16 + l15][kk * 32 + l4 * 8];
#pragma unroll
      for (int n = 0; n < NF; n++) b[n] = *(const bf16x8*)&Bs[wc + n * 16 + l15][kk * 32 + l4 * 8];
#pragma unroll
      for (int m = 0; m < 4; m++)
#pragma unroll
        for (int n = 0; n < NF; n++)
          acc[m][n] = __builtin_amdgcn_mfma_f32_16x16x32_bf16(a[m], b[n], acc[m][n], 0, 0, 0);
    }
    __syncthreads();
  }

#pragma unroll
  for (int m = 0; m < 4; m++) {
    const int rbase = brow + wr + m * 16 + l4 * 4;
#pragma unroll
    for (int n = 0; n < NF; n++) {
      const int cc = bcol + wc + n * 16 + l15;
#pragma unroll
      for (int j = 0; j < 4; j++) {
        const int rr = rbase + j;
        if (rr >= M) continue;
        float val = acc[m][n][j];
        if (bias) val += bias[cc];
        if constexpr (EPI == 1) val = fmaxf(val, 0.f);
        if constexpr (sizeof(TC) == 2)
          C[(size_t)rr * N + cc] = f2bf(val);
        else
          C[(size_t)rr * N + cc] = val;
      }
    }
  }
}

// ---------------------------------------------------------------------------
// Fused: h = relu( LN(agg @ Wo + h) * lng + lnb ) gated.  BM=BN=N=128, K=512.
// In-place update of h (each row owned by exactly one block).
// ---------------------------------------------------------------------------
__global__ __launch_bounds__(256) void gemm_wo_ln(
    const unsigned short* __restrict__ Aagg, const unsigned short* __restrict__ Bt, // [128][512]
    const float* __restrict__ Kf, const float* __restrict__ gv,
    const float* __restrict__ lng, const float* __restrict__ lnb,
    const float* __restrict__ bl, unsigned short* __restrict__ h, int M) {
  constexpr int BM = 128, BK = 128, PAD = 8, K = 512, N = 128;
  __shared__ unsigned short As[BM][BK + PAD];
  __shared__ unsigned short Bs[N][BK + PAD];
  const int tid = threadIdx.x;
  const int wave = tid >> 6, lane = tid & 63;
  const int l15 = lane & 15, l4 = lane >> 4;
  const int brow = blockIdx.y * BM;
  const int wr = (wave & 1) * 64;
  const int wc = (wave >> 1) * 64;

  f32x4 acc[4][4] = {};
  const int aRow = tid >> 1;
  const int aCol0 = (tid & 1) * 64;

  for (int k0 = 0; k0 < K; k0 += BK) {
    {
      const int gr = brow + aRow;
      const bool ok = (gr < M);
      const unsigned short* srow = Aagg + (size_t)gr * K + k0 + aCol0;
#pragma unroll
      for (int j = 0; j < 8; j++) {
        u16x8 val = {};
        if (ok) val = *(const u16x8*)(srow + j * 8);
        *(u16x8*)&As[aRow][aCol0 + j * 8] = val;
      }
    }
    {
      const unsigned short* srow = Bt + (size_t)aRow * K + k0 + aCol0;
#pragma unroll
      for (int j = 0; j < 8; j++) *(u16x8*)&Bs[aRow][aCol0 + j * 8] = *(const u16x8*)(srow + j * 8);
    }
    __syncthreads();
#pragma unroll
    for (int kk = 0; kk < 4; kk++) {
      bf16x8 a[4], b[4];
#pragma unroll
      for (int m = 0; m < 4; m++) a[m] = *(const bf16x8*)&As[wr + m * 16 + l15][kk * 32 + l4 * 8];
#pragma unroll
      for (int n = 0; n < 4; n++) b[n] = *(const bf16x8*)&Bs[wc + n * 16 + l15][kk * 32 + l4 * 8];
#pragma unroll
      for (int m = 0; m < 4; m++)
#pragma unroll
        for (int n = 0; n < 4; n++)
          acc[m][n] = __builtin_amdgcn_mfma_f32_16x16x32_bf16(a[m], b[n], acc[m][n], 0, 0, 0);
    }
    __syncthreads();
  }

  // add residual h
#pragma unroll
  for (int m = 0; m < 4; m++)
#pragma unroll
    for (int j = 0; j < 4; j++) {
      const int rr = brow + wr + m * 16 + l4 * 4 + j;
      if (rr >= M) continue;
#pragma unroll
      for (int n = 0; n < 4; n++) {
        const int cc = wc + n * 16 + l15;
        acc[m][n][j] += bf2f(h[(size_t)rr * N + cc]);
      }
    }

  // cross-wave per-row sum/sumsq via LDS scratch (reuse As; all waves past barrier)
  float* redS = (float*)&As[0][0];  // [128][2]
  float* redQ = redS + 256;         // [128][2]
  const int wavecol = wave >> 1;
#pragma unroll
  for (int m = 0; m < 4; m++)
#pragma unroll
    for (int j = 0; j < 4; j++) {
      float s = 0.f, q = 0.f;
#pragma unroll
      for (int n = 0; n < 4; n++) {
        float x = acc[m][n][j];
        s += x;
        q += x * x;
      }
#pragma unroll
      for (int off = 1; off < 16; off <<= 1) {
        s += __shfl_xor(s, off, 64);
        q += __shfl_xor(q, off, 64);
      }
      if (l15 == 0) {
        const int r = wr + m * 16 + l4 * 4 + j;
        redS[r * 2 + wavecol] = s;
        redQ[r * 2 + wavecol] = q;
      }
    }
  __syncthreads();

#pragma unroll
  for (int m = 0; m < 4; m++)
#pragma unroll
    for (int j = 0; j < 4; j++) {
      const int rloc = wr + m * 16 + l4 * 4 + j;
      const int rr = brow + rloc;
      if (rr >= M) continue;
      const float sum = redS[rloc * 2 + 0] + redS[rloc * 2 + 1];
      const float sq = redQ[rloc * 2 + 0] + redQ[rloc * 2 + 1];
      const float mean = sum * (1.f / 128.f);
      const float var = sq * (1.f / 128.f) - mean * mean;
      const float rs = rsqrtf(var + LN_EPS);
      const float kn = Kf[rr];
#pragma unroll
      for (int n = 0; n < 4; n++) {
        const int cc = wc + n * 16 + l15;
        const float y = (acc[m][n][j] - mean) * rs * lng[cc] + lnb[cc];
        const float g = 1.f / (1.f + __expf(-(kn * gv[cc] + gv[128 + cc])));
        h[(size_t)rr * N + cc] = f2bf(fmaxf(y * (1.f + g) + bl[cc], 0.f));
      }
    }
}

// ---------------------------------------------------------------------------
// all weight transposes (f32 -> bf16, [N][K] layout) in one launch
// ---------------------------------------------------------------------------
__global__ void transp_all(const float* __restrict__ W_in, const float* __restrict__ W_out,
                           const float* __restrict__ Wv, const float* __restrict__ Wo,
                           unsigned short* __restrict__ Wint, unsigned short* __restrict__ Woutt,
                           unsigned short* __restrict__ Wvt, unsigned short* __restrict__ Wot) {
  int idx = blockIdx.x * 256 + threadIdx.x;
  if (idx < 16384) {  // Wint [128][128] <- W_in [128][128]
    int n = idx >> 7, k = idx & 127;
    Wint[idx] = f2bf(W_in[k * 128 + n]);
    return;
  }
  idx -= 16384;
  if (idx < 8192) {  // Woutt [64][128] <- W_out [128][64]
    int n = idx >> 7, k = idx & 127;
    Woutt[idx] = f2bf(W_out[k * 64 + n]);
    return;
  }
  idx -= 8192;
  if (idx < 3 * 65536) {  // Wvt [3][512][128] <- Wv [3][128][512]
    int l = idx >> 16, r = idx & 65535;
    int n = r >> 7, k = r & 127;
    Wvt[idx] = f2bf(Wv[l * 65536 + k * 512 + n]);
    return;
  }
  idx -= 3 * 65536;
  if (idx < 3 * 65536) {  // Wot [3][128][512] <- Wo [3][512][128]
    int l = idx >> 16, r = idx & 65535;
    int n = r >> 9, k = r & 511;
    Wot[idx] = f2bf(Wo[l * 65536 + k * 128 + n]);
  }
}

// ---------------------------------------------------------------------------
// CSR build (multi-block scan)
// ---------------------------------------------------------------------------
__global__ void zero_int(int* __restrict__ p, int n) {
  int i = blockIdx.x * blockDim.x + threadIdx.x;
  if (i < n) p[i] = 0;
}

__global__ void histo_kernel(const int* __restrict__ dst, int* __restrict__ deg, int E) {
  int e = blockIdx.x * blockDim.x + threadIdx.x;
  if (e < E) atomicAdd(&deg[dst[e]], 1);
}

__global__ __launch_bounds__(1024) void scan_blocks(
    const int* __restrict__ deg, int* __restrict__ rowptr, int* __restrict__ blocksum, int N) {
  __shared__ int lds[1024];
  const int tid = threadIdx.x;
  const int i = blockIdx.x * 1024 + tid;
  int x = (i < N) ? deg[i] : 0;
  lds[tid] = x;
  __syncthreads();
  for (int off = 1; off < 1024; off <<= 1) {
    int t = (tid >= off) ? lds[tid - off] : 0;
    __syncthreads();
    lds[tid] += t;
    __syncthreads();
  }
  if (i < N) rowptr[i] = lds[tid] - x;
  if (tid == 1023) blocksum[blockIdx.x] = lds[1023];
}

__global__ void scan_sums(int* __restrict__ blocksum, int* __restrict__ rowptr, int NB, int N) {
  if (threadIdx.x == 0 && blockIdx.x == 0) {
    int run = 0;
    for (int b = 0; b < NB; b++) {
      int t = blocksum[b];
      blocksum[b] = run;
      run += t;
    }
    rowptr[N] = run;
  }
}

__global__ void scan_apply(int* __restrict__ rowptr, int* __restrict__ cursor,
                           const int* __restrict__ blocksum, int N) {
  int i = blockIdx.x * blockDim.x + threadIdx.x;
  if (i < N) {
    int val = rowptr[i] + blocksum[i >> 10];
    rowptr[i] = val;
    cursor[i] = val;
  }
}

__global__ void scatter_kernel(const int* __restrict__ src, const int* __restrict__ dst,
                               int* __restrict__ cursor, int* __restrict__ esrc, int E) {
  int e = blockIdx.x * blockDim.x + threadIdx.x;
  if (e < E) {
    int d = dst[e];
    int pos = atomicAdd(&cursor[d], 1);
    esrc[pos] = src[e];
  }
}

// ---------------------------------------------------------------------------
// layer_pre, 5 blocks: fold attention/gate vectors through the weights.
// ---------------------------------------------------------------------------
__global__ __launch_bounds__(256) void layer_pre(
    const float* __restrict__ wq, const float* __restrict__ wv,
    const float* __restrict__ att_l, const float* __restrict__ wkw,
    const float* __restrict__ wkb, const float* __restrict__ gw,
    const float* __restrict__ gb,
    float* __restrict__ wqv_a, float* __restrict__ kk, float* __restrict__ gv) {
  const int tid = threadIdx.x;
  const int blk = blockIdx.x;
  if (blk < 4) {
    int idx = blk * 256 + tid;
    int k = idx >> 3, o = idx & 7;
    float s = 0.f;
    if (o < 4) {
      const float* w = wq + (size_t)k * QV + o * DD;
      const float* a = att_l + o * 3 * DD + DD;  // a_q
      for (int d = 0; d < DD; d++) s += w[d] * a[d];
    } else {
      int h = o - 4;
      const float* w = wv + (size_t)k * QV + h * DD;
      const float* a = att_l + h * 3 * DD + 2 * DD;  // a_v
      for (int d = 0; d < DD; d++) s += w[d] * a[d];
    }
    wqv_a[idx] = s;
  } else {
    if (tid < DD) {
      float s1 = 0.f, s0 = 0.f;
      for (int d = 0; d < DD; d++) {
        float g = gw[(size_t)d * DD + tid];
        s1 += wkw[d] * g;
        s0 += wkb[d] * g;
      }
      gv[tid] = s1;
      gv[DD + tid] = s0 + gb[tid];
    }
    if (tid >= 128 && tid < 136) {
      int t = tid - 128;
      int h = t & 3;
      const float* a = att_l + h * 3 * DD;  // a_k
      const float* w = (t < 4) ? wkw : wkb;
      float s = 0.f;
      for (int d = 0; d < DD; d++) s += w[d] * a[d];
      kk[t] = s;
    }
  }
}

// ---------------------------------------------------------------------------
// node_pre2: skq[n,h] = K[n]*kk1[h]+kk0[h] + h[n,:]·wqv_a[:,h]
//            svb[n,h] = h[n,:]·wqv_a[:,4+h].  One wave per node. h is bf16.
// ---------------------------------------------------------------------------
__global__ __launch_bounds__(256) void node_pre2(
    const unsigned short* __restrict__ h, const float* __restrict__ Kf,
    const float* __restrict__ wqv_a, const float* __restrict__ kk,
    float* __restrict__ skq, float* __restrict__ svb, int N) {
  __shared__ float W[DD][8];
  __shared__ float kkl[8];
  const int tid = threadIdx.x;
  for (int i = tid; i < DD * 8; i += 256) W[i >> 3][i & 7] = wqv_a[i];
  if (tid < 8) kkl[tid] = kk[tid];
  __syncthreads();
  const int wid = tid >> 6, lane = tid & 63;
  const int n = blockIdx.x * 4 + wid;
  if (n >= N) return;
  const float h0 = bf2f(h[(size_t)n * DD + lane]);
  const float h1 = bf2f(h[(size_t)n * DD + lane + 64]);
  float r[8];
#pragma unroll
  for (int o = 0; o < 8; o++) r[o] = wave_sum(h0 * W[lane][o] + h1 * W[lane + 64][o]);
  if (lane == 0) {
    const float kn = Kf[n];
    *reinterpret_cast<float4*>(skq + (size_t)n * 4) =
        make_float4(r[0] + kn * kkl[0] + kkl[4], r[1] + kn * kkl[1] + kkl[5],
                    r[2] + kn * kkl[2] + kkl[6], r[3] + kn * kkl[3] + kkl[7]);
    *reinterpret_cast<float4*>(svb + (size_t)n * 4) = make_float4(r[4], r[5], r[6], r[7]);
  }
}

// ---------------------------------------------------------------------------
// attn_aggregate: single pass per dst node (one wave). Edge indices are
// prefetched 64-at-a-time (coalesced) + shfl-broadcast; unroll x2 so two
// independent v-row gathers are in flight. Lane owns cols [lane*8, lane*8+8);
// head = lane>>4. Normalization once at the end (scores O(1), clamp 60).
// ---------------------------------------------------------------------------
__global__ __launch_bounds__(256) void attn_aggregate(
    const int* __restrict__ rowptr, const int* __restrict__ esrc,
    const float* __restrict__ skq, const float* __restrict__ svb,
    const unsigned short* __restrict__ v, unsigned short* __restrict__ agg, int N) {
  const int wid = threadIdx.x >> 6;
  const int lane = threadIdx.x & 63;
  const int n = blockIdx.x * 4 + wid;
  if (n >= N) return;
  const int beg = rowptr[n];
  const int end = rowptr[n + 1];
  const int hh = lane >> 4;
  const float kq = skq[(size_t)n * HH + hh];

  float sumw = 0.f;
  float acc[8] = {0.f, 0.f, 0.f, 0.f, 0.f, 0.f, 0.f, 0.f};

  for (int base = beg; base < end; base += 64) {
    const int cnt = min(64, end - base);
    int myidx = 0;
    if (lane < cnt) myidx = esrc[base + lane];
    int j = 0;
    for (; j + 2 <= cnt; j += 2) {
      const int s0 = __shfl(myidx, j, 64);
      const int s1 = __shfl(myidx, j + 1, 64);
      float sc0 = kq + svb[(size_t)s0 * HH + hh];
      float sc1 = kq + svb[(size_t)s1 * HH + hh];
      const u16x8 vr0 = *(const u16x8*)(v + (size_t)s0 * QV + lane * 8);
      const u16x8 vr1 = *(const u16x8*)(v + (size_t)s1 * QV + lane * 8);
      sc0 = sc0 > 0.f ? sc0 : NEG_SLOPE * sc0;
      sc1 = sc1 > 0.f ? sc1 : NEG_SLOPE * sc1;
      const float ex0 = __expf(fminf(sc0, 60.f));
      const float ex1 = __expf(fminf(sc1, 60.f));
      sumw += ex0 + ex1;
#pragma unroll
      for (int t = 0; t < 8; t++) acc[t] += ex0 * bf2f(vr0[t]) + ex1 * bf2f(vr1[t]);
    }
    if (j < cnt) {
      const int s0 = __shfl(myidx, j, 64);
      float sc0 = kq + svb[(size_t)s0 * HH + hh];
      const u16x8 vr0 = *(const u16x8*)(v + (size_t)s0 * QV + lane * 8);
      sc0 = sc0 > 0.f ? sc0 : NEG_SLOPE * sc0;
      const float ex0 = __expf(fminf(sc0, 60.f));
      sumw += ex0;
#pragma unroll
      for (int t = 0; t < 8; t++) acc[t] += ex0 * bf2f(vr0[t]);
    }
  }
  const float inv = (end > beg) ? 1.f / sumw : 0.f;
  u16x8 outv;
#pragma unroll
  for (int t = 0; t < 8; t++) outv[t] = f2bf(acc[t] * inv);
  *(u16x8*)(agg + (size_t)n * QV + lane * 8) = outv;
}

// ---------------------------------------------------------------------------
extern "C" void kernel_launch(void* const* d_in, const int* in_sizes, int n_in,
                              void* d_out, int out_size, void* d_ws, size_t ws_size,
                              hipStream_t stream) {
  const float* x = (const float*)d_in[0];
  const int* edge = (const int*)d_in[1];
  const float* Kf = (const float*)d_in[2];
  const float* W_in = (const float*)d_in[3];
  const float* b_in = (const float*)d_in[4];
  const float* Wk_w = (const float*)d_in[5];
  const float* Wk_b = (const float*)d_in[6];
  const float* Wq = (const float*)d_in[7];
  const float* Wv = (const float*)d_in[8];
  const float* att = (const float*)d_in[9];
  const float* Wo = (const float*)d_in[10];
  const float* b_l = (const float*)d_in[11];
  const float* ln_g = (const float*)d_in[12];
  const float* ln_b = (const float*)d_in[13];
  const float* gate_w = (const float*)d_in[14];
  const float* gate_b = (const float*)d_in[15];
  const float* W_out = (const float*)d_in[16];
  const float* b_out = (const float*)d_in[17];
  float* out = (float*)d_out;

  const int* src = edge;
  const int* dst = edge + EE;

  // ---- workspace carve-up ----
  char* w = (char*)d_ws;
  auto alloc = [&](size_t bytes) {
    char* p = w;
    w += (bytes + 255) & ~(size_t)255;
    return p;
  };
  unsigned short* h = (unsigned short*)alloc((size_t)NN * DD * 2);
  unsigned short* v = (unsigned short*)alloc((size_t)NN * QV * 2);
  unsigned short* agg = (unsigned short*)alloc((size_t)NN * QV * 2);
  float* skq = (float*)alloc((size_t)NN * HH * 4);
  float* svb = (float*)alloc((size_t)NN * HH * 4);
  float* wqv_a = (float*)alloc(DD * 8 * 4);
  float* kk = (float*)alloc(8 * 4);
  float* gv = (float*)alloc(2 * DD * 4);
  int* deg = (int*)alloc((size_t)NN * 4);
  int* rowptr = (int*)alloc((size_t)(NN + 1) * 4);
  int* cursor = (int*)alloc((size_t)NN * 4);
  int* esrc = (int*)alloc((size_t)EE * 4);
  int* blocksum = (int*)alloc((size_t)64 * 4);
  unsigned short* Wint = (unsigned short*)alloc((size_t)DD * DD * 2);
  unsigned short* Woutt = (unsigned short*)alloc((size_t)64 * DD * 2);
  unsigned short* Wvt = (unsigned short*)alloc((size_t)LL * QV * DD * 2);  // [3][512][128]
  unsigned short* Wot = (unsigned short*)alloc((size_t)LL * DD * QV * 2);  // [3][128][512]

  dim3 blk(256);
  const int NB = cdiv(NN, 1024);
  const int GY = cdiv(NN, 128);  // 391

  // ---- CSR build ----
  zero_int<<<cdiv(NN, 256), blk, 0, stream>>>(deg, NN);
  histo_kernel<<<cdiv(EE, 256), blk, 0, stream>>>(dst, deg, EE);
  scan_blocks<<<NB, 1024, 0, stream>>>(deg, rowptr, blocksum, NN);
  scan_sums<<<1, 64, 0, stream>>>(blocksum, rowptr, NB, NN);
  scan_apply<<<cdiv(NN, 256), blk, 0, stream>>>(rowptr, cursor, blocksum, NN);
  scatter_kernel<<<cdiv(EE, 256), blk, 0, stream>>>(src, dst, cursor, esrc, EE);

  // ---- all weight transposes in one launch ----
  transp_all<<<cdiv(16384 + 8192 + 2 * 3 * 65536, 256), blk, 0, stream>>>(
      W_in, W_out, Wv, Wo, Wint, Woutt, Wvt, Wot);

  // ---- h = relu(x @ W_in + b_in)  (bf16 out) ----
  gemm_mfma<float, unsigned short, 1, 128><<<dim3(1, GY), blk, 0, stream>>>(
      x, Wint, b_in, h, NN, DD, DD);

  for (int l = 0; l < LL; l++) {
    const float* wkw = Wk_w + (size_t)l * DD;
    const float* wkb = Wk_b + (size_t)l * DD;
    const float* wq = Wq + (size_t)l * DD * QV;
    const float* wv = Wv + (size_t)l * DD * QV;
    const float* att_l = att + (size_t)l * HH * 3 * DD;
    const float* bl = b_l + (size_t)l * DD;
    const float* lng = ln_g + (size_t)l * DD;
    const float* lnb = ln_b + (size_t)l * DD;
    const float* gw = gate_w + (size_t)l * DD * DD;
    const float* gb = gate_b + (size_t)l * DD;

    layer_pre<<<5, blk, 0, stream>>>(wq, wv, att_l, wkw, wkb, gw, gb, wqv_a, kk, gv);

    // v = h @ wv  (bf16 out)
    gemm_mfma<unsigned short, unsigned short, 0, 128><<<dim3(QV / 128, GY), blk, 0, stream>>>(
        h, Wvt + (size_t)l * QV * DD, nullptr, v, NN, QV, DD);

    // per-node score components
    node_pre2<<<cdiv(NN, 4), blk, 0, stream>>>(h, Kf, wqv_a, kk, skq, svb, NN);

    // single-pass softmax + aggregation
    attn_aggregate<<<cdiv(NN, 4), blk, 0, stream>>>(rowptr, esrc, skq, svb, v, agg, NN);

    // h = relu(LN(agg @ wo + h)*lng+lnb * (1+sigmoid(K*gv1+gv0)) + bl)  -- fused, in place
    gemm_wo_ln<<<dim3(1, GY), blk, 0, stream>>>(
        agg, Wot + (size_t)l * DD * QV, Kf, gv, lng, lnb, bl, h, NN);
  }

  // ---- out = h @ W_out + b_out  (f32) ----
  gemm_mfma<unsigned short, float, 0, 64><<<dim3(1, GY), blk, 0, stream>>>(
      h, Woutt, b_out, out, NN, 64, DD);
}

// Round 8
// 723.971 us; speedup vs baseline: 1.9418x; 1.0251x over previous
//
#include <hip/hip_runtime.h>

constexpr int NN = 50000;   // nodes
constexpr int EE = 400000;  // edges
constexpr int DD = 128;     // feature dim
constexpr int HH = 4;       // heads
constexpr int LL = 3;       // layers
constexpr int QV = DD * HH; // 512
constexpr float NEG_SLOPE = 0.01f;
constexpr float LN_EPS = 1e-5f;

static inline int cdiv(int a, int b) { return (a + b - 1) / b; }

#define DEVINL __device__ __forceinline__

typedef __attribute__((ext_vector_type(8))) short bf16x8;
typedef __attribute__((ext_vector_type(8))) unsigned short u16x8;
typedef __attribute__((ext_vector_type(4))) float f32x4;

DEVINL float wave_sum(float v) {
#pragma unroll
  for (int off = 32; off; off >>= 1) v += __shfl_xor(v, off, 64);
  return v;
}

DEVINL float bf2f(unsigned short u) {
  unsigned int t = ((unsigned int)u) << 16;
  float f;
  __builtin_memcpy(&f, &t, 4);
  return f;
}
DEVINL unsigned short f2bf(float f) {
  unsigned int u;
  __builtin_memcpy(&u, &f, 4);
  u = u + 0x7fffu + ((u >> 16) & 1u);  // RNE
  return (unsigned short)(u >> 16);
}

// ---------------------------------------------------------------------------
// MFMA GEMM, BM=64: C[M,N] = A[M,K] @ B[K,N], B TRANSPOSED as Bt[N][K] bf16.
// BN in {64,128}. 256 threads = 4 waves; wave owns 16 rows x BN cols.
// EPI: 0=+bias(if non-null), 1=relu(+bias).
// ---------------------------------------------------------------------------
template <typename TA, typename TC, int EPI, int BN>
__global__ __launch_bounds__(256) void gemm64(
    const TA* __restrict__ A, const unsigned short* __restrict__ Bt,
    const float* __restrict__ bias, TC* __restrict__ C, int M, int N, int K) {
  constexpr int BM = 64, BK = 128, PAD = 8;
  constexpr int NF = BN / 16;  // 8 for BN=128, 4 for BN=64
  __shared__ unsigned short As[BM][BK + PAD];
  __shared__ unsigned short Bs[BN][BK + PAD];
  const int tid = threadIdx.x;
  const int wave = tid >> 6, lane = tid & 63;
  const int l15 = lane & 15, l4 = lane >> 4;
  const int brow = blockIdx.y * BM, bcol = blockIdx.x * BN;
  const int wr = wave * 16;

  f32x4 acc[NF] = {};

  for (int k0 = 0; k0 < K; k0 += BK) {
    {  // stage A: 64 rows, thread: row=tid>>2, col0=(tid&3)*32
      const int row = tid >> 2, col0 = (tid & 3) * 32;
      const int gr = brow + row;
      const bool ok = (gr < M);
      if constexpr (sizeof(TA) == 2) {
        const unsigned short* srow = (const unsigned short*)A + (size_t)gr * K + k0 + col0;
#pragma unroll
        for (int j = 0; j < 4; j++) {
          u16x8 val = {};
          if (ok) val = *(const u16x8*)(srow + j * 8);
          *(u16x8*)&As[row][col0 + j * 8] = val;
        }
      } else {
        const float* srow = (const float*)A + (size_t)gr * K + k0 + col0;
#pragma unroll
        for (int j = 0; j < 4; j++) {
          u16x8 val = {};
          if (ok) {
            float4 f0 = *(const float4*)(srow + j * 8);
            float4 f1 = *(const float4*)(srow + j * 8 + 4);
            val[0] = f2bf(f0.x); val[1] = f2bf(f0.y); val[2] = f2bf(f0.z); val[3] = f2bf(f0.w);
            val[4] = f2bf(f1.x); val[5] = f2bf(f1.y); val[6] = f2bf(f1.z); val[7] = f2bf(f1.w);
          }
          *(u16x8*)&As[row][col0 + j * 8] = val;
        }
      }
    }
    if constexpr (BN == 128) {  // stage B: row=tid>>1, col0=(tid&1)*64
      const int row = tid >> 1, col0 = (tid & 1) * 64;
      const unsigned short* srow = Bt + (size_t)(bcol + row) * K + k0 + col0;
#pragma unroll
      for (int j = 0; j < 8; j++) *(u16x8*)&Bs[row][col0 + j * 8] = *(const u16x8*)(srow + j * 8);
    } else {
      const int row = tid >> 2, col0 = (tid & 3) * 32;
      const unsigned short* srow = Bt + (size_t)(bcol + row) * K + k0 + col0;
#pragma unroll
      for (int j = 0; j < 4; j++) *(u16x8*)&Bs[row][col0 + j * 8] = *(const u16x8*)(srow + j * 8);
    }
    __syncthreads();
#pragma unroll
    for (int kk = 0; kk < 4; kk++) {
      bf16x8 a = *(const bf16x8*)&As[wr + l15][kk * 32 + l4 * 8];
      bf16x8 b[NF];
#pragma unroll
      for (int n = 0; n < NF; n++) b[n] = *(const bf16x8*)&Bs[n * 16 + l15][kk * 32 + l4 * 8];
#pragma unroll
      for (int n = 0; n < NF; n++)
        acc[n] = __builtin_amdgcn_mfma_f32_16x16x32_bf16(a, b[n], acc[n], 0, 0, 0);
    }
    __syncthreads();
  }

#pragma unroll
  for (int n = 0; n < NF; n++) {
    const int cc = bcol + n * 16 + l15;
#pragma unroll
    for (int j = 0; j < 4; j++) {
      const int rr = brow + wr + l4 * 4 + j;
      if (rr >= M) continue;
      float val = acc[n][j];
      if (bias) val += bias[cc];
      if constexpr (EPI == 1) val = fmaxf(val, 0.f);
      if constexpr (sizeof(TC) == 2)
        C[(size_t)rr * N + cc] = f2bf(val);
      else
        C[(size_t)rr * N + cc] = val;
    }
  }
}

// ---------------------------------------------------------------------------
// Fused: h = relu( (LN(agg @ Wo + h)*lng+lnb) * (1+sigmoid(K*gv1+gv0)) + bl )
// BM=64, N=128, K=512. Each wave owns 16 full rows -> in-wave LN reduce.
// In-place update of h.
// ---------------------------------------------------------------------------
__global__ __launch_bounds__(256) void gemm_wo_ln(
    const unsigned short* __restrict__ Aagg, const unsigned short* __restrict__ Bt,
    const float* __restrict__ Kf, const float* __restrict__ gv,
    const float* __restrict__ lng, const float* __restrict__ lnb,
    const float* __restrict__ bl, unsigned short* __restrict__ h, int M) {
  constexpr int BM = 64, BK = 128, PAD = 8, K = 512, N = 128;
  __shared__ unsigned short As[BM][BK + PAD];
  __shared__ unsigned short Bs[N][BK + PAD];
  const int tid = threadIdx.x;
  const int wave = tid >> 6, lane = tid & 63;
  const int l15 = lane & 15, l4 = lane >> 4;
  const int brow = blockIdx.y * BM;
  const int wr = wave * 16;

  f32x4 acc[8] = {};

  for (int k0 = 0; k0 < K; k0 += BK) {
    {
      const int row = tid >> 2, col0 = (tid & 3) * 32;
      const int gr = brow + row;
      const bool ok = (gr < M);
      const unsigned short* srow = Aagg + (size_t)gr * K + k0 + col0;
#pragma unroll
      for (int j = 0; j < 4; j++) {
        u16x8 val = {};
        if (ok) val = *(const u16x8*)(srow + j * 8);
        *(u16x8*)&As[row][col0 + j * 8] = val;
      }
    }
    {
      const int row = tid >> 1, col0 = (tid & 1) * 64;
      const unsigned short* srow = Bt + (size_t)row * K + k0 + col0;
#pragma unroll
      for (int j = 0; j < 8; j++) *(u16x8*)&Bs[row][col0 + j * 8] = *(const u16x8*)(srow + j * 8);
    }
    __syncthreads();
#pragma unroll
    for (int kk = 0; kk < 4; kk++) {
      bf16x8 a = *(const bf16x8*)&As[wr + l15][kk * 32 + l4 * 8];
      bf16x8 b[8];
#pragma unroll
      for (int n = 0; n < 8; n++) b[n] = *(const bf16x8*)&Bs[n * 16 + l15][kk * 32 + l4 * 8];
#pragma unroll
      for (int n = 0; n < 8; n++)
        acc[n] = __builtin_amdgcn_mfma_f32_16x16x32_bf16(a, b[n], acc[n], 0, 0, 0);
    }
    __syncthreads();
  }

  // residual + in-wave LN + gate + relu, write h in place
#pragma unroll
  for (int j = 0; j < 4; j++) {
    const int rr = brow + wr + l4 * 4 + j;
    const bool ok = (rr < M);
    float s = 0.f, q = 0.f;
#pragma unroll
    for (int n = 0; n < 8; n++) {
      const int cc = n * 16 + l15;
      float val = acc[n][j] + (ok ? bf2f(h[(size_t)rr * N + cc]) : 0.f);
      acc[n][j] = val;
      s += val;
      q += val * val;
    }
#pragma unroll
    for (int off = 1; off < 16; off <<= 1) {
      s += __shfl_xor(s, off, 64);
      q += __shfl_xor(q, off, 64);
    }
    const float mean = s * (1.f / 128.f);
    const float var = q * (1.f / 128.f) - mean * mean;
    const float rs = rsqrtf(var + LN_EPS);
    const float kn = ok ? Kf[rr] : 0.f;
#pragma unroll
    for (int n = 0; n < 8; n++) {
      const int cc = n * 16 + l15;
      const float y = (acc[n][j] - mean) * rs * lng[cc] + lnb[cc];
      const float g = 1.f / (1.f + __expf(-(kn * gv[cc] + gv[128 + cc])));
      if (ok) h[(size_t)rr * N + cc] = f2bf(fmaxf(y * (1.f + g) + bl[cc], 0.f));
    }
  }
}

// ---------------------------------------------------------------------------
// all weight transposes (f32 -> bf16, [N][K] layout) in one launch
// ---------------------------------------------------------------------------
__global__ void transp_all(const float* __restrict__ W_in, const float* __restrict__ W_out,
                           const float* __restrict__ Wv, const float* __restrict__ Wo,
                           unsigned short* __restrict__ Wint, unsigned short* __restrict__ Woutt,
                           unsigned short* __restrict__ Wvt, unsigned short* __restrict__ Wot) {
  int idx = blockIdx.x * 256 + threadIdx.x;
  if (idx < 16384) {  // Wint [128][128] <- W_in [128][128]
    int n = idx >> 7, k = idx & 127;
    Wint[idx] = f2bf(W_in[k * 128 + n]);
    return;
  }
  idx -= 16384;
  if (idx < 8192) {  // Woutt [64][128] <- W_out [128][64]
    int n = idx >> 7, k = idx & 127;
    Woutt[idx] = f2bf(W_out[k * 64 + n]);
    return;
  }
  idx -= 8192;
  if (idx < 3 * 65536) {  // Wvt [3][512][128] <- Wv [3][128][512]
    int l = idx >> 16, r = idx & 65535;
    int n = r >> 7, k = r & 127;
    Wvt[idx] = f2bf(Wv[l * 65536 + k * 512 + n]);
    return;
  }
  idx -= 3 * 65536;
  if (idx < 3 * 65536) {  // Wot [3][128][512] <- Wo [3][512][128]
    int l = idx >> 16, r = idx & 65535;
    int n = r >> 9, k = r & 511;
    Wot[idx] = f2bf(Wo[l * 65536 + k * 128 + n]);
  }
}

// ---------------------------------------------------------------------------
// CSR build (multi-block scan)
// ---------------------------------------------------------------------------
__global__ void zero_int(int* __restrict__ p, int n) {
  int i = blockIdx.x * blockDim.x + threadIdx.x;
  if (i < n) p[i] = 0;
}

__global__ void histo_kernel(const int* __restrict__ dst, int* __restrict__ deg, int E) {
  int e = blockIdx.x * blockDim.x + threadIdx.x;
  if (e < E) atomicAdd(&deg[dst[e]], 1);
}

__global__ __launch_bounds__(1024) void scan_blocks(
    const int* __restrict__ deg, int* __restrict__ rowptr, int* __restrict__ blocksum, int N) {
  __shared__ int lds[1024];
  const int tid = threadIdx.x;
  const int i = blockIdx.x * 1024 + tid;
  int x = (i < N) ? deg[i] : 0;
  lds[tid] = x;
  __syncthreads();
  for (int off = 1; off < 1024; off <<= 1) {
    int t = (tid >= off) ? lds[tid - off] : 0;
    __syncthreads();
    lds[tid] += t;
    __syncthreads();
  }
  if (i < N) rowptr[i] = lds[tid] - x;
  if (tid == 1023) blocksum[blockIdx.x] = lds[1023];
}

__global__ void scan_sums(int* __restrict__ blocksum, int* __restrict__ rowptr, int NB, int N) {
  if (threadIdx.x == 0 && blockIdx.x == 0) {
    int run = 0;
    for (int b = 0; b < NB; b++) {
      int t = blocksum[b];
      blocksum[b] = run;
      run += t;
    }
    rowptr[N] = run;
  }
}

__global__ void scan_apply(int* __restrict__ rowptr, int* __restrict__ cursor,
                           const int* __restrict__ blocksum, int N) {
  int i = blockIdx.x * blockDim.x + threadIdx.x;
  if (i < N) {
    int val = rowptr[i] + blocksum[i >> 10];
    rowptr[i] = val;
    cursor[i] = val;
  }
}

__global__ void scatter_kernel(const int* __restrict__ src, const int* __restrict__ dst,
                               int* __restrict__ cursor, int* __restrict__ esrc,
                               int* __restrict__ edst, int E) {
  int e = blockIdx.x * blockDim.x + threadIdx.x;
  if (e < E) {
    int d = dst[e];
    int pos = atomicAdd(&cursor[d], 1);
    esrc[pos] = src[e];
    edst[pos] = d;
  }
}

// ---------------------------------------------------------------------------
// layer_pre: one wave per output dot-product (1288 waves = 322 blocks).
//   wid<1024: wqv_a ; 1024..1151: gv1 ; 1152..1279: gv0+gb ; 1280..1287: kk
// ---------------------------------------------------------------------------
__global__ __launch_bounds__(256) void layer_pre(
    const float* __restrict__ wq, const float* __restrict__ wv,
    const float* __restrict__ att_l, const float* __restrict__ wkw,
    const float* __restrict__ wkb, const float* __restrict__ gw,
    const float* __restrict__ gb,
    float* __restrict__ wqv_a, float* __restrict__ kk, float* __restrict__ gv) {
  const int wid = blockIdx.x * 4 + (threadIdx.x >> 6);
  const int lane = threadIdx.x & 63;
  if (wid < 1024) {
    int k = wid >> 3, o = wid & 7;
    const float* w;
    const float* a;
    if (o < 4) {
      w = wq + (size_t)k * QV + o * DD;
      a = att_l + o * 3 * DD + DD;  // a_q
    } else {
      w = wv + (size_t)k * QV + (o - 4) * DD;
      a = att_l + (o - 4) * 3 * DD + 2 * DD;  // a_v
    }
    float s = wave_sum(w[lane] * a[lane] + w[lane + 64] * a[lane + 64]);
    if (lane == 0) wqv_a[wid] = s;
  } else if (wid < 1152) {
    int c = wid - 1024;
    float s = wave_sum(wkw[lane] * gw[(size_t)lane * DD + c] +
                       wkw[lane + 64] * gw[(size_t)(lane + 64) * DD + c]);
    if (lane == 0) gv[c] = s;
  } else if (wid < 1280) {
    int c = wid - 1152;
    float s = wave_sum(wkb[lane] * gw[(size_t)lane * DD + c] +
                       wkb[lane + 64] * gw[(size_t)(lane + 64) * DD + c]);
    if (lane == 0) gv[DD + c] = s + gb[c];
  } else if (wid < 1288) {
    int t = wid - 1280;
    const float* a = att_l + (t & 3) * 3 * DD;  // a_k
    const float* w = (t < 4) ? wkw : wkb;
    float s = wave_sum(w[lane] * a[lane] + w[lane + 64] * a[lane + 64]);
    if (lane == 0) kk[t] = s;
  }
}

// ---------------------------------------------------------------------------
// node_pre2: skq[n,h] = K[n]*kk1[h]+kk0[h] + h[n,:]·wqv_a[:,h]
//            svb[n,h] = h[n,:]·wqv_a[:,4+h].  One wave per node. h is bf16.
// ---------------------------------------------------------------------------
__global__ __launch_bounds__(256) void node_pre2(
    const unsigned short* __restrict__ h, const float* __restrict__ Kf,
    const float* __restrict__ wqv_a, const float* __restrict__ kk,
    float* __restrict__ skq, float* __restrict__ svb, int N) {
  __shared__ float W[DD][8];
  __shared__ float kkl[8];
  const int tid = threadIdx.x;
  for (int i = tid; i < DD * 8; i += 256) W[i >> 3][i & 7] = wqv_a[i];
  if (tid < 8) kkl[tid] = kk[tid];
  __syncthreads();
  const int wid = tid >> 6, lane = tid & 63;
  const int n = blockIdx.x * 4 + wid;
  if (n >= N) return;
  const float h0 = bf2f(h[(size_t)n * DD + lane]);
  const float h1 = bf2f(h[(size_t)n * DD + lane + 64]);
  float r[8];
#pragma unroll
  for (int o = 0; o < 8; o++) r[o] = wave_sum(h0 * W[lane][o] + h1 * W[lane + 64][o]);
  if (lane == 0) {
    const float kn = Kf[n];
    *reinterpret_cast<float4*>(skq + (size_t)n * 4) =
        make_float4(r[0] + kn * kkl[0] + kkl[4], r[1] + kn * kkl[1] + kkl[5],
                    r[2] + kn * kkl[2] + kkl[6], r[3] + kn * kkl[3] + kkl[7]);
    *reinterpret_cast<float4*>(svb + (size_t)n * 4) = make_float4(r[4], r[5], r[6], r[7]);
  }
}

// ---------------------------------------------------------------------------
// edge_ex: per-edge softmax weights, head-major planes ext[h][e].
// ---------------------------------------------------------------------------
__global__ __launch_bounds__(256) void edge_ex(
    const int* __restrict__ esrc, const int* __restrict__ edst,
    const float* __restrict__ skq, const float* __restrict__ svb,
    float* __restrict__ ext, int E) {
  const int e = blockIdx.x * 256 + threadIdx.x;
  if (e >= E) return;
  const int s = esrc[e], d = edst[e];
  const float4 sv = *(const float4*)(svb + (size_t)s * 4);
  const float4 kq = *(const float4*)(skq + (size_t)d * 4);
  float sc[4] = {kq.x + sv.x, kq.y + sv.y, kq.z + sv.z, kq.w + sv.w};
#pragma unroll
  for (int hh = 0; hh < 4; hh++) {
    float v = sc[hh] > 0.f ? sc[hh] : NEG_SLOPE * sc[hh];
    ext[(size_t)hh * E + e] = __expf(fminf(v, 60.f));
  }
}

// ---------------------------------------------------------------------------
// attn_aggregate: per dst node (one wave), weights precomputed in ext.
// Lane owns cols [lane*8, +8); head = lane>>4 -> reads plane ext[hh].
// Unroll x4: 4 independent v-row gathers in flight.
// ---------------------------------------------------------------------------
__global__ __launch_bounds__(256) void attn_aggregate(
    const int* __restrict__ rowptr, const int* __restrict__ esrc,
    const float* __restrict__ ext, const unsigned short* __restrict__ v,
    unsigned short* __restrict__ agg, int N, int E) {
  const int wid = threadIdx.x >> 6;
  const int lane = threadIdx.x & 63;
  const int n = blockIdx.x * 4 + wid;
  if (n >= N) return;
  const int beg = rowptr[n];
  const int end = rowptr[n + 1];
  const float* exh = ext + (size_t)(lane >> 4) * E;

  float sumw = 0.f;
  float acc[8] = {0.f, 0.f, 0.f, 0.f, 0.f, 0.f, 0.f, 0.f};

  for (int base = beg; base < end; base += 64) {
    const int cnt = min(64, end - base);
    int myidx = 0;
    if (lane < cnt) myidx = esrc[base + lane];
    int j = 0;
    for (; j + 4 <= cnt; j += 4) {
      const int s0 = __shfl(myidx, j, 64);
      const int s1 = __shfl(myidx, j + 1, 64);
      const int s2 = __shfl(myidx, j + 2, 64);
      const int s3 = __shfl(myidx, j + 3, 64);
      const float e0 = exh[base + j];
      const float e1 = exh[base + j + 1];
      const float e2 = exh[base + j + 2];
      const float e3 = exh[base + j + 3];
      const u16x8 v0 = *(const u16x8*)(v + (size_t)s0 * QV + lane * 8);
      const u16x8 v1 = *(const u16x8*)(v + (size_t)s1 * QV + lane * 8);
      const u16x8 v2 = *(const u16x8*)(v + (size_t)s2 * QV + lane * 8);
      const u16x8 v3 = *(const u16x8*)(v + (size_t)s3 * QV + lane * 8);
      sumw += (e0 + e1) + (e2 + e3);
#pragma unroll
      for (int t = 0; t < 8; t++)
        acc[t] += e0 * bf2f(v0[t]) + e1 * bf2f(v1[t]) + e2 * bf2f(v2[t]) + e3 * bf2f(v3[t]);
    }
    for (; j < cnt; j++) {
      const int s0 = __shfl(myidx, j, 64);
      const float e0 = exh[base + j];
      const u16x8 v0 = *(const u16x8*)(v + (size_t)s0 * QV + lane * 8);
      sumw += e0;
#pragma unroll
      for (int t = 0; t < 8; t++) acc[t] += e0 * bf2f(v0[t]);
    }
  }
  const float inv = (end > beg) ? 1.f / sumw : 0.f;
  u16x8 outv;
#pragma unroll
  for (int t = 0; t < 8; t++) outv[t] = f2bf(acc[t] * inv);
  *(u16x8*)(agg + (size_t)n * QV + lane * 8) = outv;
}

// ---------------------------------------------------------------------------
extern "C" void kernel_launch(void* const* d_in, const int* in_sizes, int n_in,
                              void* d_out, int out_size, void* d_ws, size_t ws_size,
                              hipStream_t stream) {
  const float* x = (const float*)d_in[0];
  const int* edge = (const int*)d_in[1];
  const float* Kf = (const float*)d_in[2];
  const float* W_in = (const float*)d_in[3];
  const float* b_in = (const float*)d_in[4];
  const float* Wk_w = (const float*)d_in[5];
  const float* Wk_b = (const float*)d_in[6];
  const float* Wq = (const float*)d_in[7];
  const float* Wv = (const float*)d_in[8];
  const float* att = (const float*)d_in[9];
  const float* Wo = (const float*)d_in[10];
  const float* b_l = (const float*)d_in[11];
  const float* ln_g = (const float*)d_in[12];
  const float* ln_b = (const float*)d_in[13];
  const float* gate_w = (const float*)d_in[14];
  const float* gate_b = (const float*)d_in[15];
  const float* W_out = (const float*)d_in[16];
  const float* b_out = (const float*)d_in[17];
  float* out = (float*)d_out;

  const int* src = edge;
  const int* dst = edge + EE;

  // ---- workspace carve-up ----
  char* w = (char*)d_ws;
  auto alloc = [&](size_t bytes) {
    char* p = w;
    w += (bytes + 255) & ~(size_t)255;
    return p;
  };
  unsigned short* h = (unsigned short*)alloc((size_t)NN * DD * 2);
  unsigned short* v = (unsigned short*)alloc((size_t)NN * QV * 2);
  unsigned short* agg = (unsigned short*)alloc((size_t)NN * QV * 2);
  float* skq = (float*)alloc((size_t)NN * HH * 4);
  float* svb = (float*)alloc((size_t)NN * HH * 4);
  float* wqv_a = (float*)alloc(DD * 8 * 4);
  float* kk = (float*)alloc(8 * 4);
  float* gv = (float*)alloc(2 * DD * 4);
  int* deg = (int*)alloc((size_t)NN * 4);
  int* rowptr = (int*)alloc((size_t)(NN + 1) * 4);
  int* cursor = (int*)alloc((size_t)NN * 4);
  int* esrc = (int*)alloc((size_t)EE * 4);
  int* edst = (int*)alloc((size_t)EE * 4);
  float* ext = (float*)alloc((size_t)HH * EE * 4);
  int* blocksum = (int*)alloc((size_t)64 * 4);
  unsigned short* Wint = (unsigned short*)alloc((size_t)DD * DD * 2);
  unsigned short* Woutt = (unsigned short*)alloc((size_t)64 * DD * 2);
  unsigned short* Wvt = (unsigned short*)alloc((size_t)LL * QV * DD * 2);  // [3][512][128]
  unsigned short* Wot = (unsigned short*)alloc((size_t)LL * DD * QV * 2);  // [3][128][512]

  dim3 blk(256);
  const int NB = cdiv(NN, 1024);
  const int GY = cdiv(NN, 64);  // 782

  // ---- CSR build ----
  zero_int<<<cdiv(NN, 256), blk, 0, stream>>>(deg, NN);
  histo_kernel<<<cdiv(EE, 256), blk, 0, stream>>>(dst, deg, EE);
  scan_blocks<<<NB, 1024, 0, stream>>>(deg, rowptr, blocksum, NN);
  scan_sums<<<1, 64, 0, stream>>>(blocksum, rowptr, NB, NN);
  scan_apply<<<cdiv(NN, 256), blk, 0, stream>>>(rowptr, cursor, blocksum, NN);
  scatter_kernel<<<cdiv(EE, 256), blk, 0, stream>>>(src, dst, cursor, esrc, edst, EE);

  // ---- all weight transposes in one launch ----
  transp_all<<<cdiv(16384 + 8192 + 2 * 3 * 65536, 256), blk, 0, stream>>>(
      W_in, W_out, Wv, Wo, Wint, Woutt, Wvt, Wot);

  // ---- h = relu(x @ W_in + b_in)  (bf16 out) ----
  gemm64<float, unsigned short, 1, 128><<<dim3(1, GY), blk, 0, stream>>>(
      x, Wint, b_in, h, NN, DD, DD);

  for (int l = 0; l < LL; l++) {
    const float* wkw = Wk_w + (size_t)l * DD;
    const float* wkb = Wk_b + (size_t)l * DD;
    const float* wq = Wq + (size_t)l * DD * QV;
    const float* wv = Wv + (size_t)l * DD * QV;
    const float* att_l = att + (size_t)l * HH * 3 * DD;
    const float* bl = b_l + (size_t)l * DD;
    const float* lng = ln_g + (size_t)l * DD;
    const float* lnb = ln_b + (size_t)l * DD;
    const float* gw = gate_w + (size_t)l * DD * DD;
    const float* gb = gate_b + (size_t)l * DD;

    layer_pre<<<cdiv(1288, 4), blk, 0, stream>>>(wq, wv, att_l, wkw, wkb, gw, gb, wqv_a, kk, gv);

    // v = h @ wv  (bf16 out)
    gemm64<unsigned short, unsigned short, 0, 128><<<dim3(QV / 128, GY), blk, 0, stream>>>(
        h, Wvt + (size_t)l * QV * DD, nullptr, v, NN, QV, DD);

    // per-node score components
    node_pre2<<<cdiv(NN, 4), blk, 0, stream>>>(h, Kf, wqv_a, kk, skq, svb, NN);

    // per-edge softmax weights
    edge_ex<<<cdiv(EE, 256), blk, 0, stream>>>(esrc, edst, skq, svb, ext, EE);

    // gather + normalize
    attn_aggregate<<<cdiv(NN, 4), blk, 0, stream>>>(rowptr, esrc, ext, v, agg, NN, EE);

    // h = relu(LN(agg @ wo + h)*lng+lnb * gate + bl)  -- fused, in place
    gemm_wo_ln<<<dim3(1, GY), blk, 0, stream>>>(
        agg, Wot + (size_t)l * DD * QV, Kf, gv, lng, lnb, bl, h, NN);
  }

  // ---- out = h @ W_out + b_out  (f32) ----
  gemm64<unsigned short, float, 0, 64><<<dim3(1, GY), blk, 0, stream>>>(
      h, Woutt, b_out, out, NN, 64, DD);
}

// Round 9
// 585.792 us; speedup vs baseline: 2.3998x; 1.2359x over previous
//
#include <hip/hip_runtime.h>

constexpr int NN = 50000;   // nodes
constexpr int EE = 400000;  // edges
constexpr int DD = 128;     // feature dim
constexpr int HH = 4;       // heads
constexpr int LL = 3;       // layers
constexpr int QV = DD * HH; // 512
constexpr float NEG_SLOPE = 0.01f;
constexpr float LN_EPS = 1e-5f;

static inline int cdiv(int a, int b) { return (a + b - 1) / b; }

#define DEVINL __device__ __forceinline__

typedef __attribute__((ext_vector_type(8))) short bf16x8;
typedef __attribute__((ext_vector_type(8))) unsigned short u16x8;
typedef __attribute__((ext_vector_type(4))) float f32x4;

DEVINL float wave_sum(float v) {
#pragma unroll
  for (int off = 32; off; off >>= 1) v += __shfl_xor(v, off, 64);
  return v;
}

DEVINL float bf2f(unsigned short u) {
  unsigned int t = ((unsigned int)u) << 16;
  float f;
  __builtin_memcpy(&f, &t, 4);
  return f;
}
DEVINL unsigned short f2bf(float f) {
  unsigned int u;
  __builtin_memcpy(&u, &f, 4);
  u = u + 0x7fffu + ((u >> 16) & 1u);  // RNE
  return (unsigned short)(u >> 16);
}

// ---------------------------------------------------------------------------
// MFMA GEMM, BM=64: C[M,N] = A[M,K] @ B[K,N], B TRANSPOSED as Bt[N][K] bf16.
// BN in {64,128}. 256 threads = 4 waves; wave owns 16 rows x BN cols.
// EPI: 0=+bias(if non-null), 1=relu(+bias).
// ---------------------------------------------------------------------------
template <typename TA, typename TC, int EPI, int BN>
__global__ __launch_bounds__(256) void gemm64(
    const TA* __restrict__ A, const unsigned short* __restrict__ Bt,
    const float* __restrict__ bias, TC* __restrict__ C, int M, int N, int K) {
  constexpr int BM = 64, BK = 128, PAD = 8;
  constexpr int NF = BN / 16;
  __shared__ unsigned short As[BM][BK + PAD];
  __shared__ unsigned short Bs[BN][BK + PAD];
  const int tid = threadIdx.x;
  const int wave = tid >> 6, lane = tid & 63;
  const int l15 = lane & 15, l4 = lane >> 4;
  const int brow = blockIdx.y * BM, bcol = blockIdx.x * BN;
  const int wr = wave * 16;

  f32x4 acc[NF] = {};

  for (int k0 = 0; k0 < K; k0 += BK) {
    {
      const int row = tid >> 2, col0 = (tid & 3) * 32;
      const int gr = brow + row;
      const bool ok = (gr < M);
      if constexpr (sizeof(TA) == 2) {
        const unsigned short* srow = (const unsigned short*)A + (size_t)gr * K + k0 + col0;
#pragma unroll
        for (int j = 0; j < 4; j++) {
          u16x8 val = {};
          if (ok) val = *(const u16x8*)(srow + j * 8);
          *(u16x8*)&As[row][col0 + j * 8] = val;
        }
      } else {
        const float* srow = (const float*)A + (size_t)gr * K + k0 + col0;
#pragma unroll
        for (int j = 0; j < 4; j++) {
          u16x8 val = {};
          if (ok) {
            float4 f0 = *(const float4*)(srow + j * 8);
            float4 f1 = *(const float4*)(srow + j * 8 + 4);
            val[0] = f2bf(f0.x); val[1] = f2bf(f0.y); val[2] = f2bf(f0.z); val[3] = f2bf(f0.w);
            val[4] = f2bf(f1.x); val[5] = f2bf(f1.y); val[6] = f2bf(f1.z); val[7] = f2bf(f1.w);
          }
          *(u16x8*)&As[row][col0 + j * 8] = val;
        }
      }
    }
    if constexpr (BN == 128) {
      const int row = tid >> 1, col0 = (tid & 1) * 64;
      const unsigned short* srow = Bt + (size_t)(bcol + row) * K + k0 + col0;
#pragma unroll
      for (int j = 0; j < 8; j++) *(u16x8*)&Bs[row][col0 + j * 8] = *(const u16x8*)(srow + j * 8);
    } else {
      const int row = tid >> 2, col0 = (tid & 3) * 32;
      const unsigned short* srow = Bt + (size_t)(bcol + row) * K + k0 + col0;
#pragma unroll
      for (int j = 0; j < 4; j++) *(u16x8*)&Bs[row][col0 + j * 8] = *(const u16x8*)(srow + j * 8);
    }
    __syncthreads();
#pragma unroll
    for (int kk = 0; kk < 4; kk++) {
      bf16x8 a = *(const bf16x8*)&As[wr + l15][kk * 32 + l4 * 8];
      bf16x8 b[NF];
#pragma unroll
      for (int n = 0; n < NF; n++) b[n] = *(const bf16x8*)&Bs[n * 16 + l15][kk * 32 + l4 * 8];
#pragma unroll
      for (int n = 0; n < NF; n++)
        acc[n] = __builtin_amdgcn_mfma_f32_16x16x32_bf16(a, b[n], acc[n], 0, 0, 0);
    }
    __syncthreads();
  }

#pragma unroll
  for (int n = 0; n < NF; n++) {
    const int cc = bcol + n * 16 + l15;
#pragma unroll
    for (int j = 0; j < 4; j++) {
      const int rr = brow + wr + l4 * 4 + j;
      if (rr >= M) continue;
      float val = acc[n][j];
      if (bias) val += bias[cc];
      if constexpr (EPI == 1) val = fmaxf(val, 0.f);
      if constexpr (sizeof(TC) == 2)
        C[(size_t)rr * N + cc] = f2bf(val);
      else
        C[(size_t)rr * N + cc] = val;
    }
  }
}

// ---------------------------------------------------------------------------
// gemm_wvo: WvoT[j][r] = Wvo[r][j], Wvo[h*128+i][j] = sum_c Wv[i,h*128+c]*Wo[h*128+c,j]
// A = Wv_l [128][512] f32; Bt = Wot_l [128][512] bf16. Grid (1, 8). K=128 single step.
// ---------------------------------------------------------------------------
__global__ __launch_bounds__(256) void gemm_wvo(
    const float* __restrict__ Wv_l, const unsigned short* __restrict__ Wot_l,
    unsigned short* __restrict__ WvoT) {
  constexpr int BK = 128, PAD = 8;
  __shared__ unsigned short As[64][BK + PAD];
  __shared__ unsigned short Bs[128][BK + PAD];
  const int tid = threadIdx.x;
  const int wave = tid >> 6, lane = tid & 63;
  const int l15 = lane & 15, l4 = lane >> 4;
  const int brow = blockIdx.y * 64;  // output row block in [0,512)
  const int hh = brow >> 7;          // head (uniform per block)
  const int wr = wave * 16;

  f32x4 acc[8] = {};
  {
    const int row = tid >> 2, col0 = (tid & 3) * 32;
    const int i = (brow + row) & 127;
    const float* srow = Wv_l + (size_t)i * QV + hh * DD + col0;
#pragma unroll
    for (int j = 0; j < 4; j++) {
      float4 f0 = *(const float4*)(srow + j * 8);
      float4 f1 = *(const float4*)(srow + j * 8 + 4);
      u16x8 val;
      val[0] = f2bf(f0.x); val[1] = f2bf(f0.y); val[2] = f2bf(f0.z); val[3] = f2bf(f0.w);
      val[4] = f2bf(f1.x); val[5] = f2bf(f1.y); val[6] = f2bf(f1.z); val[7] = f2bf(f1.w);
      *(u16x8*)&As[row][col0 + j * 8] = val;
    }
  }
  {
    const int row = tid >> 1, col0 = (tid & 1) * 64;
    const unsigned short* srow = Wot_l + (size_t)row * QV + hh * DD + col0;
#pragma unroll
    for (int j = 0; j < 8; j++) *(u16x8*)&Bs[row][col0 + j * 8] = *(const u16x8*)(srow + j * 8);
  }
  __syncthreads();
#pragma unroll
  for (int kk = 0; kk < 4; kk++) {
    bf16x8 a = *(const bf16x8*)&As[wr + l15][kk * 32 + l4 * 8];
    bf16x8 b[8];
#pragma unroll
    for (int n = 0; n < 8; n++) b[n] = *(const bf16x8*)&Bs[n * 16 + l15][kk * 32 + l4 * 8];
#pragma unroll
    for (int n = 0; n < 8; n++)
      acc[n] = __builtin_amdgcn_mfma_f32_16x16x32_bf16(a, b[n], acc[n], 0, 0, 0);
  }
  // write transposed: WvoT[cc][rr]
#pragma unroll
  for (int n = 0; n < 8; n++) {
    const int cc = n * 16 + l15;
#pragma unroll
    for (int j = 0; j < 4; j++) {
      const int rr = brow + wr + l4 * 4 + j;
      WvoT[(size_t)cc * 512 + rr] = f2bf(acc[n][j]);
    }
  }
}

// ---------------------------------------------------------------------------
// Fused: h = relu( (LN(agh @ Wvo + h)*lng+lnb) * (1+sigmoid(K*gv1+gv0)) + bl )
// BM=64, N=128, K=512. Wave owns 16 full rows -> in-wave LN. In-place h.
// ---------------------------------------------------------------------------
__global__ __launch_bounds__(256) void gemm_wo_ln(
    const unsigned short* __restrict__ Aagg, const unsigned short* __restrict__ Bt,
    const float* __restrict__ Kf, const float* __restrict__ gv,
    const float* __restrict__ lng, const float* __restrict__ lnb,
    const float* __restrict__ bl, unsigned short* __restrict__ h, int M) {
  constexpr int BM = 64, BK = 128, PAD = 8, K = 512, N = 128;
  __shared__ unsigned short As[BM][BK + PAD];
  __shared__ unsigned short Bs[N][BK + PAD];
  const int tid = threadIdx.x;
  const int wave = tid >> 6, lane = tid & 63;
  const int l15 = lane & 15, l4 = lane >> 4;
  const int brow = blockIdx.y * BM;
  const int wr = wave * 16;

  f32x4 acc[8] = {};

  for (int k0 = 0; k0 < K; k0 += BK) {
    {
      const int row = tid >> 2, col0 = (tid & 3) * 32;
      const int gr = brow + row;
      const bool ok = (gr < M);
      const unsigned short* srow = Aagg + (size_t)gr * K + k0 + col0;
#pragma unroll
      for (int j = 0; j < 4; j++) {
        u16x8 val = {};
        if (ok) val = *(const u16x8*)(srow + j * 8);
        *(u16x8*)&As[row][col0 + j * 8] = val;
      }
    }
    {
      const int row = tid >> 1, col0 = (tid & 1) * 64;
      const unsigned short* srow = Bt + (size_t)row * K + k0 + col0;
#pragma unroll
      for (int j = 0; j < 8; j++) *(u16x8*)&Bs[row][col0 + j * 8] = *(const u16x8*)(srow + j * 8);
    }
    __syncthreads();
#pragma unroll
    for (int kk = 0; kk < 4; kk++) {
      bf16x8 a = *(const bf16x8*)&As[wr + l15][kk * 32 + l4 * 8];
      bf16x8 b[8];
#pragma unroll
      for (int n = 0; n < 8; n++) b[n] = *(const bf16x8*)&Bs[n * 16 + l15][kk * 32 + l4 * 8];
#pragma unroll
      for (int n = 0; n < 8; n++)
        acc[n] = __builtin_amdgcn_mfma_f32_16x16x32_bf16(a, b[n], acc[n], 0, 0, 0);
    }
    __syncthreads();
  }

#pragma unroll
  for (int j = 0; j < 4; j++) {
    const int rr = brow + wr + l4 * 4 + j;
    const bool ok = (rr < M);
    float s = 0.f, q = 0.f;
#pragma unroll
    for (int n = 0; n < 8; n++) {
      const int cc = n * 16 + l15;
      float val = acc[n][j] + (ok ? bf2f(h[(size_t)rr * N + cc]) : 0.f);
      acc[n][j] = val;
      s += val;
      q += val * val;
    }
#pragma unroll
    for (int off = 1; off < 16; off <<= 1) {
      s += __shfl_xor(s, off, 64);
      q += __shfl_xor(q, off, 64);
    }
    const float mean = s * (1.f / 128.f);
    const float var = q * (1.f / 128.f) - mean * mean;
    const float rs = rsqrtf(var + LN_EPS);
    const float kn = ok ? Kf[rr] : 0.f;
#pragma unroll
    for (int n = 0; n < 8; n++) {
      const int cc = n * 16 + l15;
      const float y = (acc[n][j] - mean) * rs * lng[cc] + lnb[cc];
      const float g = 1.f / (1.f + __expf(-(kn * gv[cc] + gv[128 + cc])));
      if (ok) h[(size_t)rr * N + cc] = f2bf(fmaxf(y * (1.f + g) + bl[cc], 0.f));
    }
  }
}

// ---------------------------------------------------------------------------
// weight transposes (f32 -> bf16, [N][K] layout): Wint, Woutt, Wot
// ---------------------------------------------------------------------------
__global__ void transp_all(const float* __restrict__ W_in, const float* __restrict__ W_out,
                           const float* __restrict__ Wo,
                           unsigned short* __restrict__ Wint, unsigned short* __restrict__ Woutt,
                           unsigned short* __restrict__ Wot) {
  int idx = blockIdx.x * 256 + threadIdx.x;
  if (idx < 16384) {  // Wint [128][128] <- W_in [128][128]
    int n = idx >> 7, k = idx & 127;
    Wint[idx] = f2bf(W_in[k * 128 + n]);
    return;
  }
  idx -= 16384;
  if (idx < 8192) {  // Woutt [64][128] <- W_out [128][64]
    int n = idx >> 7, k = idx & 127;
    Woutt[idx] = f2bf(W_out[k * 64 + n]);
    return;
  }
  idx -= 8192;
  if (idx < 3 * 65536) {  // Wot [3][128][512] <- Wo [3][512][128]
    int l = idx >> 16, r = idx & 65535;
    int n = r >> 9, k = r & 511;
    Wot[idx] = f2bf(Wo[l * 65536 + k * 128 + n]);
  }
}

// ---------------------------------------------------------------------------
// CSR build (multi-block scan)
// ---------------------------------------------------------------------------
__global__ void zero_int(int* __restrict__ p, int n) {
  int i = blockIdx.x * blockDim.x + threadIdx.x;
  if (i < n) p[i] = 0;
}

__global__ void histo_kernel(const int* __restrict__ dst, int* __restrict__ deg, int E) {
  int e = blockIdx.x * blockDim.x + threadIdx.x;
  if (e < E) atomicAdd(&deg[dst[e]], 1);
}

__global__ __launch_bounds__(1024) void scan_blocks(
    const int* __restrict__ deg, int* __restrict__ rowptr, int* __restrict__ blocksum, int N) {
  __shared__ int lds[1024];
  const int tid = threadIdx.x;
  const int i = blockIdx.x * 1024 + tid;
  int x = (i < N) ? deg[i] : 0;
  lds[tid] = x;
  __syncthreads();
  for (int off = 1; off < 1024; off <<= 1) {
    int t = (tid >= off) ? lds[tid - off] : 0;
    __syncthreads();
    lds[tid] += t;
    __syncthreads();
  }
  if (i < N) rowptr[i] = lds[tid] - x;
  if (tid == 1023) blocksum[blockIdx.x] = lds[1023];
}

__global__ void scan_sums(int* __restrict__ blocksum, int* __restrict__ rowptr, int NB, int N) {
  if (threadIdx.x == 0 && blockIdx.x == 0) {
    int run = 0;
    for (int b = 0; b < NB; b++) {
      int t = blocksum[b];
      blocksum[b] = run;
      run += t;
    }
    rowptr[N] = run;
  }
}

__global__ void scan_apply(int* __restrict__ rowptr, int* __restrict__ cursor,
                           const int* __restrict__ blocksum, int N) {
  int i = blockIdx.x * blockDim.x + threadIdx.x;
  if (i < N) {
    int val = rowptr[i] + blocksum[i >> 10];
    rowptr[i] = val;
    cursor[i] = val;
  }
}

__global__ void scatter_kernel(const int* __restrict__ src, const int* __restrict__ dst,
                               int* __restrict__ cursor, int* __restrict__ esrc,
                               int* __restrict__ edst, int E) {
  int e = blockIdx.x * blockDim.x + threadIdx.x;
  if (e < E) {
    int d = dst[e];
    int pos = atomicAdd(&cursor[d], 1);
    esrc[pos] = src[e];
    edst[pos] = d;
  }
}

// ---------------------------------------------------------------------------
// layer_pre: one wave per output dot-product (1288 waves = 322 blocks).
// ---------------------------------------------------------------------------
__global__ __launch_bounds__(256) void layer_pre(
    const float* __restrict__ wq, const float* __restrict__ wv,
    const float* __restrict__ att_l, const float* __restrict__ wkw,
    const float* __restrict__ wkb, const float* __restrict__ gw,
    const float* __restrict__ gb,
    float* __restrict__ wqv_a, float* __restrict__ kk, float* __restrict__ gv) {
  const int wid = blockIdx.x * 4 + (threadIdx.x >> 6);
  const int lane = threadIdx.x & 63;
  if (wid < 1024) {
    int k = wid >> 3, o = wid & 7;
    const float* w;
    const float* a;
    if (o < 4) {
      w = wq + (size_t)k * QV + o * DD;
      a = att_l + o * 3 * DD + DD;  // a_q
    } else {
      w = wv + (size_t)k * QV + (o - 4) * DD;
      a = att_l + (o - 4) * 3 * DD + 2 * DD;  // a_v
    }
    float s = wave_sum(w[lane] * a[lane] + w[lane + 64] * a[lane + 64]);
    if (lane == 0) wqv_a[wid] = s;
  } else if (wid < 1152) {
    int c = wid - 1024;
    float s = wave_sum(wkw[lane] * gw[(size_t)lane * DD + c] +
                       wkw[lane + 64] * gw[(size_t)(lane + 64) * DD + c]);
    if (lane == 0) gv[c] = s;
  } else if (wid < 1280) {
    int c = wid - 1152;
    float s = wave_sum(wkb[lane] * gw[(size_t)lane * DD + c] +
                       wkb[lane + 64] * gw[(size_t)(lane + 64) * DD + c]);
    if (lane == 0) gv[DD + c] = s + gb[c];
  } else if (wid < 1288) {
    int t = wid - 1280;
    const float* a = att_l + (t & 3) * 3 * DD;  // a_k
    const float* w = (t < 4) ? wkw : wkb;
    float s = wave_sum(w[lane] * a[lane] + w[lane + 64] * a[lane + 64]);
    if (lane == 0) kk[t] = s;
  }
}

// ---------------------------------------------------------------------------
// node_pre2: skq[n,h] = K[n]*kk1[h]+kk0[h] + h[n,:]·wqv_a[:,h]
//            svb[n,h] = h[n,:]·wqv_a[:,4+h].  One wave per node. h is bf16.
// ---------------------------------------------------------------------------
__global__ __launch_bounds__(256) void node_pre2(
    const unsigned short* __restrict__ h, const float* __restrict__ Kf,
    const float* __restrict__ wqv_a, const float* __restrict__ kk,
    float* __restrict__ skq, float* __restrict__ svb, int N) {
  __shared__ float W[DD][8];
  __shared__ float kkl[8];
  const int tid = threadIdx.x;
  for (int i = tid; i < DD * 8; i += 256) W[i >> 3][i & 7] = wqv_a[i];
  if (tid < 8) kkl[tid] = kk[tid];
  __syncthreads();
  const int wid = tid >> 6, lane = tid & 63;
  const int n = blockIdx.x * 4 + wid;
  if (n >= N) return;
  const float h0 = bf2f(h[(size_t)n * DD + lane]);
  const float h1 = bf2f(h[(size_t)n * DD + lane + 64]);
  float r[8];
#pragma unroll
  for (int o = 0; o < 8; o++) r[o] = wave_sum(h0 * W[lane][o] + h1 * W[lane + 64][o]);
  if (lane == 0) {
    const float kn = Kf[n];
    *reinterpret_cast<float4*>(skq + (size_t)n * 4) =
        make_float4(r[0] + kn * kkl[0] + kkl[4], r[1] + kn * kkl[1] + kkl[5],
                    r[2] + kn * kkl[2] + kkl[6], r[3] + kn * kkl[3] + kkl[7]);
    *reinterpret_cast<float4*>(svb + (size_t)n * 4) = make_float4(r[4], r[5], r[6], r[7]);
  }
}

// ---------------------------------------------------------------------------
// edge_ex: per-edge softmax weights, AoS float4 per edge (all 4 heads).
// ---------------------------------------------------------------------------
__global__ __launch_bounds__(256) void edge_ex(
    const int* __restrict__ esrc, const int* __restrict__ edst,
    const float* __restrict__ skq, const float* __restrict__ svb,
    float4* __restrict__ ext4, int E) {
  const int e = blockIdx.x * 256 + threadIdx.x;
  if (e >= E) return;
  const int s = esrc[e], d = edst[e];
  const float4 sv = *(const float4*)(svb + (size_t)s * 4);
  const float4 kq = *(const float4*)(skq + (size_t)d * 4);
  float sc[4] = {kq.x + sv.x, kq.y + sv.y, kq.z + sv.z, kq.w + sv.w};
  float ex[4];
#pragma unroll
  for (int hh = 0; hh < 4; hh++) {
    float vv = sc[hh] > 0.f ? sc[hh] : NEG_SLOPE * sc[hh];
    ex[hh] = __expf(fminf(vv, 60.f));
  }
  ext4[e] = make_float4(ex[0], ex[1], ex[2], ex[3]);
}

// ---------------------------------------------------------------------------
// attn_gather: agh[n][h*128+c] = (Σ_e ex^h_e · h[src_e][c]) / Σ_e ex^h_e.
// One wave per node; lane owns cols {lane*2, lane*2+1} of h (4B gather/lane).
// h table is 12.8 MB (L2/L3-resident) vs 51.2 MB v — 4x less gather traffic.
// Unroll x8: 8 independent gathers in flight.
// ---------------------------------------------------------------------------
__global__ __launch_bounds__(256) void attn_gather(
    const int* __restrict__ rowptr, const int* __restrict__ esrc,
    const float4* __restrict__ ext4, const unsigned short* __restrict__ h,
    unsigned short* __restrict__ agh, int N) {
  const int wid = threadIdx.x >> 6;
  const int lane = threadIdx.x & 63;
  const int n = blockIdx.x * 4 + wid;
  if (n >= N) return;
  const int beg = rowptr[n];
  const int end = rowptr[n + 1];
  const int c0 = lane * 2;

  float a0[4] = {}, a1[4] = {};
  float sumw[4] = {};

  for (int base = beg; base < end; base += 64) {
    const int cnt = min(64, end - base);
    int myidx = 0;
    if (lane < cnt) myidx = esrc[base + lane];
    int j = 0;
    for (; j + 8 <= cnt; j += 8) {
      int s[8];
      unsigned int wv[8];
      float4 ee[8];
#pragma unroll
      for (int u = 0; u < 8; u++) s[u] = __shfl(myidx, j + u, 64);
#pragma unroll
      for (int u = 0; u < 8; u++) wv[u] = *(const unsigned int*)(h + (size_t)s[u] * DD + c0);
#pragma unroll
      for (int u = 0; u < 8; u++) ee[u] = ext4[base + j + u];
#pragma unroll
      for (int u = 0; u < 8; u++) {
        const float lo = bf2f((unsigned short)(wv[u] & 0xffffu));
        const float hi = bf2f((unsigned short)(wv[u] >> 16));
        a0[0] += ee[u].x * lo; a1[0] += ee[u].x * hi;
        a0[1] += ee[u].y * lo; a1[1] += ee[u].y * hi;
        a0[2] += ee[u].z * lo; a1[2] += ee[u].z * hi;
        a0[3] += ee[u].w * lo; a1[3] += ee[u].w * hi;
        sumw[0] += ee[u].x; sumw[1] += ee[u].y;
        sumw[2] += ee[u].z; sumw[3] += ee[u].w;
      }
    }
    for (; j < cnt; j++) {
      const int s0 = __shfl(myidx, j, 64);
      const unsigned int w0 = *(const unsigned int*)(h + (size_t)s0 * DD + c0);
      const float4 ee = ext4[base + j];
      const float lo = bf2f((unsigned short)(w0 & 0xffffu));
      const float hi = bf2f((unsigned short)(w0 >> 16));
      a0[0] += ee.x * lo; a1[0] += ee.x * hi;
      a0[1] += ee.y * lo; a1[1] += ee.y * hi;
      a0[2] += ee.z * lo; a1[2] += ee.z * hi;
      a0[3] += ee.w * lo; a1[3] += ee.w * hi;
      sumw[0] += ee.x; sumw[1] += ee.y; sumw[2] += ee.z; sumw[3] += ee.w;
    }
  }
  const bool has = (end > beg);
#pragma unroll
  for (int hh = 0; hh < 4; hh++) {
    const float inv = has ? 1.f / sumw[hh] : 0.f;
    const unsigned int packed =
        (unsigned int)f2bf(a0[hh] * inv) | ((unsigned int)f2bf(a1[hh] * inv) << 16);
    *(unsigned int*)(agh + (size_t)n * QV + hh * DD + c0) = packed;
  }
}

// ---------------------------------------------------------------------------
extern "C" void kernel_launch(void* const* d_in, const int* in_sizes, int n_in,
                              void* d_out, int out_size, void* d_ws, size_t ws_size,
                              hipStream_t stream) {
  const float* x = (const float*)d_in[0];
  const int* edge = (const int*)d_in[1];
  const float* Kf = (const float*)d_in[2];
  const float* W_in = (const float*)d_in[3];
  const float* b_in = (const float*)d_in[4];
  const float* Wk_w = (const float*)d_in[5];
  const float* Wk_b = (const float*)d_in[6];
  const float* Wq = (const float*)d_in[7];
  const float* Wv = (const float*)d_in[8];
  const float* att = (const float*)d_in[9];
  const float* Wo = (const float*)d_in[10];
  const float* b_l = (const float*)d_in[11];
  const float* ln_g = (const float*)d_in[12];
  const float* ln_b = (const float*)d_in[13];
  const float* gate_w = (const float*)d_in[14];
  const float* gate_b = (const float*)d_in[15];
  const float* W_out = (const float*)d_in[16];
  const float* b_out = (const float*)d_in[17];
  float* out = (float*)d_out;

  const int* src = edge;
  const int* dst = edge + EE;

  // ---- workspace carve-up ----
  char* w = (char*)d_ws;
  auto alloc = [&](size_t bytes) {
    char* p = w;
    w += (bytes + 255) & ~(size_t)255;
    return p;
  };
  unsigned short* h = (unsigned short*)alloc((size_t)NN * DD * 2);     // 12.8 MB
  unsigned short* agh = (unsigned short*)alloc((size_t)NN * QV * 2);   // 51.2 MB
  float* skq = (float*)alloc((size_t)NN * HH * 4);
  float* svb = (float*)alloc((size_t)NN * HH * 4);
  float* wqv_a = (float*)alloc(DD * 8 * 4);
  float* kk = (float*)alloc(8 * 4);
  float* gv = (float*)alloc(2 * DD * 4);
  int* deg = (int*)alloc((size_t)NN * 4);
  int* rowptr = (int*)alloc((size_t)(NN + 1) * 4);
  int* cursor = (int*)alloc((size_t)NN * 4);
  int* esrc = (int*)alloc((size_t)EE * 4);
  int* edst = (int*)alloc((size_t)EE * 4);
  float4* ext4 = (float4*)alloc((size_t)EE * 16);
  int* blocksum = (int*)alloc((size_t)64 * 4);
  unsigned short* Wint = (unsigned short*)alloc((size_t)DD * DD * 2);
  unsigned short* Woutt = (unsigned short*)alloc((size_t)64 * DD * 2);
  unsigned short* Wot = (unsigned short*)alloc((size_t)LL * DD * QV * 2);  // [3][128][512]
  unsigned short* WvoT = (unsigned short*)alloc((size_t)DD * QV * 2);      // [128][512]

  dim3 blk(256);
  const int NB = cdiv(NN, 1024);
  const int GY = cdiv(NN, 64);  // 782

  // ---- CSR build ----
  zero_int<<<cdiv(NN, 256), blk, 0, stream>>>(deg, NN);
  histo_kernel<<<cdiv(EE, 256), blk, 0, stream>>>(dst, deg, EE);
  scan_blocks<<<NB, 1024, 0, stream>>>(deg, rowptr, blocksum, NN);
  scan_sums<<<1, 64, 0, stream>>>(blocksum, rowptr, NB, NN);
  scan_apply<<<cdiv(NN, 256), blk, 0, stream>>>(rowptr, cursor, blocksum, NN);
  scatter_kernel<<<cdiv(EE, 256), blk, 0, stream>>>(src, dst, cursor, esrc, edst, EE);

  // ---- weight transposes ----
  transp_all<<<cdiv(16384 + 8192 + 3 * 65536, 256), blk, 0, stream>>>(
      W_in, W_out, Wo, Wint, Woutt, Wot);

  // ---- h = relu(x @ W_in + b_in)  (bf16 out) ----
  gemm64<float, unsigned short, 1, 128><<<dim3(1, GY), blk, 0, stream>>>(
      x, Wint, b_in, h, NN, DD, DD);

  for (int l = 0; l < LL; l++) {
    const float* wkw = Wk_w + (size_t)l * DD;
    const float* wkb = Wk_b + (size_t)l * DD;
    const float* wq = Wq + (size_t)l * DD * QV;
    const float* wv = Wv + (size_t)l * DD * QV;
    const float* att_l = att + (size_t)l * HH * 3 * DD;
    const float* bl = b_l + (size_t)l * DD;
    const float* lng = ln_g + (size_t)l * DD;
    const float* lnb = ln_b + (size_t)l * DD;
    const float* gw = gate_w + (size_t)l * DD * DD;
    const float* gb = gate_b + (size_t)l * DD;

    layer_pre<<<cdiv(1288, 4), blk, 0, stream>>>(wq, wv, att_l, wkw, wkb, gw, gb, wqv_a, kk, gv);

    // WvoT = (blockdiag(Wv_h) @ Wo)^T  (tiny)
    gemm_wvo<<<dim3(1, 8), blk, 0, stream>>>(wv, Wot + (size_t)l * DD * QV, WvoT);

    // per-node score components
    node_pre2<<<cdiv(NN, 4), blk, 0, stream>>>(h, Kf, wqv_a, kk, skq, svb, NN);

    // per-edge softmax weights (AoS float4)
    edge_ex<<<cdiv(EE, 256), blk, 0, stream>>>(esrc, edst, skq, svb, ext4, EE);

    // gather h-rows weighted per head -> agh
    attn_gather<<<cdiv(NN, 4), blk, 0, stream>>>(rowptr, esrc, ext4, h, agh, NN);

    // h = relu(LN(agh @ Wvo + h)*lng+lnb * gate + bl)  -- fused, in place
    gemm_wo_ln<<<dim3(1, GY), blk, 0, stream>>>(
        agh, WvoT, Kf, gv, lng, lnb, bl, h, NN);
  }

  // ---- out = h @ W_out + b_out  (f32) ----
  gemm64<unsigned short, float, 0, 64><<<dim3(1, GY), blk, 0, stream>>>(
      h, Woutt, b_out, out, NN, 64, DD);
}